// Round 1
// baseline (2966.796 us; speedup 1.0000x reference)
//
#include <hip/hip_runtime.h>

// ---------------------------------------------------------------------------
// CCALayer: sizes
//   spt (1,5,640,10,10)  qry (75,640,10,10)
//   Q=75, way=5, C=640, Cf=64, spatial P=100 (10x10), items = 375
// Output: sim (75,5) [375 floats] ++ qry_pooled (75,640) [48000 floats]
// ---------------------------------------------------------------------------

#define NQ    75
#define NWAY  5
#define NITEM 375

// ws layout (float offsets)
#define OFF_SC  0            // centered support   5*640*100   = 320000
#define OFF_QC  320000       // centered query    75*640*100   = 4800000
#define OFF_SF  5120000      // sf  5*64*100 = 32000
#define OFF_QF  5152000      // qf 75*64*100 = 480000
#define OFF_RA  5632000      // branch-A result 375*10000
#define OFF_RB  9382000      // branch-B result 375*10000
#define OFF_AS  13132000     // attn_s 375*100
#define OFF_AQ  13169500     // attn_q 375*100
#define OFF_PRM 13207000     // folded params (2536 floats)

// prm layout:
// [0..143]   W1eff  [ds][i]        (c2 conv1 (+bn1+proj+bnp) folded to 16->1)
// [144..159] A[i]   (c1 proj*bnp scale)
// [160..175] Bp[i]  (c1 proj*bnp shift)
// [176..191] S2c2[o], [192..207] B2c2[o]   (c2 bn2)
// [208..216] w2c1 (c1 conv over first dims), [217..225] w1c1 (c1 conv over second dims)
// [226] S2 [227] B2 [228] S1 [229] B1 [230] Cf
// [232..2535] w2r [tap][i][o]  (c2 conv2 weights repacked)

__global__ __launch_bounds__(256) void k_prep(
    const float* __restrict__ c1c2w, const float* __restrict__ c1bn2,
    const float* __restrict__ c1c1w, const float* __restrict__ c1bn1,
    const float* __restrict__ c1pj,  const float* __restrict__ c1bnp,
    const float* __restrict__ c2c2w, const float* __restrict__ c2bn2,
    const float* __restrict__ c2c1w, const float* __restrict__ c2bn1,
    const float* __restrict__ c2pj,  const float* __restrict__ c2bnp,
    float* __restrict__ prm)
{
  const int t = threadIdx.x;
  const float eps = 1e-5f;

  // W1eff [ds][i]
  for (int idx = t; idx < 144; idx += 256) {
    int ds = idx / 16, i = idx % 16;
    float spv = c2bnp[0] / sqrtf(c2bnp[3] + eps);
    float acc = 0.f;
    for (int o = 0; o < 16; ++o) {
      float s1 = c2bn1[o] / sqrtf(c2bn1[48 + o] + eps);
      acc += c2pj[o] * s1 * c2c1w[(o * 16 + i) * 9 + ds];
    }
    prm[idx] = spv * acc;
  }
  // A, Bp (c1 proj folded with c1 bnp)
  for (int i = t; i < 16; i += 256) {
    float s = c1bnp[i] / sqrtf(c1bnp[48 + i] + eps);
    prm[144 + i] = s * c1pj[i];
    prm[160 + i] = c1bnp[16 + i] - c1bnp[32 + i] * s;
  }
  // c2 bn2
  for (int o = t; o < 16; o += 256) {
    float s = c2bn2[o] / sqrtf(c2bn2[48 + o] + eps);
    prm[176 + o] = s;
    prm[192 + o] = c2bn2[16 + o] - c2bn2[32 + o] * s;
  }
  // c1 conv kernels (9 taps each)
  for (int k = t; k < 9; k += 256) {
    prm[208 + k] = c1c2w[k];
    prm[217 + k] = c1c1w[k];
  }
  if (t == 0) {
    float S2 = c1bn2[0] / sqrtf(c1bn2[3] + eps);
    prm[226] = S2;
    prm[227] = c1bn2[1] - c1bn2[2] * S2;
    float S1 = c1bn1[0] / sqrtf(c1bn1[3] + eps);
    prm[228] = S1;
    prm[229] = c1bn1[1] - c1bn1[2] * S1;
    float spv = c2bnp[0] / sqrtf(c2bnp[3] + eps);
    float k0 = 0.f;
    for (int o = 0; o < 16; ++o) {
      float s1 = c2bn1[o] / sqrtf(c2bn1[48 + o] + eps);
      k0 += c2pj[o] * (c2bn1[16 + o] - c2bn1[32 + o] * s1);
    }
    prm[230] = spv * (k0 - c2bnp[2]) + c2bnp[1];
    prm[231] = 0.f;
  }
  // repack c2 conv2 weights: w2r[tap][i][o]
  for (int idx = t; idx < 2304; idx += 256) {
    int tap = idx >> 8, rem = idx & 255, i = rem >> 4, o = rem & 15;
    prm[232 + idx] = c2c2w[(o * 16 + i) * 9 + tap];
  }
}

// ---------------------------------------------------------------------------
// center features (subtract channel mean); also emit qry_pooled
__global__ __launch_bounds__(128) void k_center(
    const float* __restrict__ spt, const float* __restrict__ qry,
    float* __restrict__ ws, float* __restrict__ out)
{
  const int b = blockIdx.x, t = threadIdx.x;
  const float* src = (b < 5) ? spt + b * 64000 : qry + (b - 5) * 64000;
  float* dst = (b < 5) ? ws + OFF_SC + b * 64000 : ws + OFF_QC + (b - 5) * 64000;
  __shared__ float mp[100];
  __shared__ float msum;
  if (t < 100) {
    float s = 0.f;
    for (int c = 0; c < 640; ++c) s += src[c * 100 + t];
    mp[t] = s * (1.f / 640.f);
  }
  __syncthreads();
  if (t == 0) { float s = 0.f; for (int p = 0; p < 100; ++p) s += mp[p]; msum = s; }
  for (int idx = t; idx < 64000; idx += 128) dst[idx] = src[idx] - mp[idx % 100];
  __syncthreads();
  if (b >= 5) {
    for (int c = t; c < 640; c += 128) {
      float s = 0.f;
      for (int p = 0; p < 100; ++p) s += src[c * 100 + p];
      out[375 + (b - 5) * 640 + c] = (s - msum) * 0.01f;
    }
  }
}

// ---------------------------------------------------------------------------
// 1x1 conv 640->64 + BN + relu + per-position L2 normalize
__global__ __launch_bounds__(512) void k_feat(
    const float* __restrict__ w1x1, const float* __restrict__ bn1x1,
    float* __restrict__ ws)
{
  const int b = blockIdx.x, t = threadIdx.x;
  const float* src = (b < 5) ? ws + OFF_SC + b * 64000 : ws + OFF_QC + (b - 5) * 64000;
  float* dst = (b < 5) ? ws + OFF_SF + b * 6400 : ws + OFF_QF + (b - 5) * 6400;

  __shared__ float xch[6400];   // [64 c][100 p] ; reused as fL[64][100]
  __shared__ float wch[4096];   // [64 o][64 c]
  __shared__ float rn[100];

  float acc[16];
  #pragma unroll
  for (int k = 0; k < 16; ++k) acc[k] = 0.f;

  const int ot = t / 25, pt = t % 25;      // valid tiles: t < 400
  const int o0 = ot * 4, p0 = pt * 4;

  for (int cc = 0; cc < 10; ++cc) {
    __syncthreads();
    for (int idx = t; idx < 6400; idx += 512) xch[idx] = src[cc * 6400 + idx];
    for (int idx = t; idx < 4096; idx += 512) {
      int o = idx >> 6, c = idx & 63;
      wch[idx] = w1x1[o * 640 + cc * 64 + c];
    }
    __syncthreads();
    if (t < 400) {
      for (int c = 0; c < 64; ++c) {
        float xv[4], wv[4];
        #pragma unroll
        for (int k = 0; k < 4; ++k) xv[k] = xch[c * 100 + p0 + k];
        #pragma unroll
        for (int j = 0; j < 4; ++j) wv[j] = wch[(o0 + j) * 64 + c];
        #pragma unroll
        for (int j = 0; j < 4; ++j)
          #pragma unroll
          for (int k = 0; k < 4; ++k) acc[j * 4 + k] += wv[j] * xv[k];
      }
    }
  }
  __syncthreads();
  float* fL = xch;
  if (t < 400) {
    #pragma unroll
    for (int j = 0; j < 4; ++j) {
      int o = o0 + j;
      float scv = bn1x1[o] / sqrtf(bn1x1[192 + o] + 1e-5f);
      float shv = bn1x1[64 + o] - bn1x1[128 + o] * scv;
      #pragma unroll
      for (int k = 0; k < 4; ++k) {
        float v = scv * acc[j * 4 + k] + shv;
        fL[o * 100 + p0 + k] = v > 0.f ? v : 0.f;
      }
    }
  }
  __syncthreads();
  if (t < 100) {
    float s = 0.f;
    for (int o = 0; o < 64; ++o) { float v = fL[o * 100 + t]; s += v * v; }
    float nr = sqrtf(s);
    rn[t] = 1.f / (nr > 1e-8f ? nr : 1e-8f);
  }
  __syncthreads();
  for (int idx = t; idx < 6400; idx += 512) dst[idx] = fL[idx] * rn[idx % 100];
}

// ---------------------------------------------------------------------------
// Fused corr + cca branch. grid = 375 items x 2 branches.
// Generic coords: f = dims the FIRST conv (conv2 kernels) acts on,
//                 s = dims the SECOND conv acts on.
// branch 0: f = uv(ij), s = hw(kl);  branch 1: f = hw, s = uv.
// LDS: [0,40000)   CORRgen, later T2
//      [40000,..)  sf(25600)+qf(25600) -> T1(40000) -> Y2 fp16(32000)
__global__ __launch_bounds__(1024) void k_cca(float* __restrict__ ws)
{
  extern __shared__ char smem[];
  float* CORR = (float*)(smem);
  float* sfL  = (float*)(smem + 40000);
  float* qfL  = (float*)(smem + 40000 + 25600);
  float* T1   = (float*)(smem + 40000);
  _Float16* Y2 = (_Float16*)(smem + 40000);

  const float* prm = ws + OFF_PRM;
  const int bid = blockIdx.x;
  const int it = bid >> 1, br = bid & 1;
  const int q = it / 5, n = it % 5;
  const int t = threadIdx.x;

  const float* sf = ws + OFF_SF + n * 6400;
  const float* qf = ws + OFF_QF + q * 6400;

  for (int idx = t; idx < 6400; idx += 1024) {
    sfL[idx] = sf[idx];
    qfL[idx] = qf[idx];
  }
  __syncthreads();

  // corr in generic layout [f*100+s]
  for (int idx = t; idx < 10000; idx += 1024) {
    int a = idx / 100, b2 = idx % 100;
    int ij = br ? b2 : a;
    int kl = br ? a : b2;
    float acc = 0.f;
    #pragma unroll 8
    for (int c = 0; c < 64; ++c) acc += sfL[c * 100 + ij] * qfL[c * 100 + kl];
    CORR[idx] = acc;
  }
  __syncthreads();

  const float S2 = prm[226], B2 = prm[227], S1 = prm[228], B1 = prm[229], Cf = prm[230];

  // c1 first conv (3x3 over f dims) + bn2 + relu -> T1
  for (int idx = t; idx < 10000; idx += 1024) {
    int f = idx / 100, s = idx % 100;
    int f1 = f / 10, f2 = f % 10;
    float acc = 0.f;
    #pragma unroll
    for (int du = 0; du < 3; ++du) {
      int f1p = f1 + du - 1;
      if ((unsigned)f1p >= 10u) continue;
      #pragma unroll
      for (int dv = 0; dv < 3; ++dv) {
        int f2p = f2 + dv - 1;
        if ((unsigned)f2p >= 10u) continue;
        acc += prm[208 + du * 3 + dv] * CORR[(f1p * 10 + f2p) * 100 + s];
      }
    }
    float v = S2 * acc + B2;
    T1[idx] = v > 0.f ? v : 0.f;
  }
  __syncthreads();

  // c1 second conv (3x3 over s dims) + bn1 -> T2 (overwrites CORR)
  float* T2 = CORR;
  for (int idx = t; idx < 10000; idx += 1024) {
    int f = idx / 100, s = idx % 100;
    int s1i = s / 10, s2i = s % 10;
    float acc = 0.f;
    #pragma unroll
    for (int dh = 0; dh < 3; ++dh) {
      int s1p = s1i + dh - 1;
      if ((unsigned)s1p >= 10u) continue;
      #pragma unroll
      for (int dw = 0; dw < 3; ++dw) {
        int s2p = s2i + dw - 1;
        if ((unsigned)s2p >= 10u) continue;
        acc += prm[217 + dh * 3 + dw] * T1[f * 100 + s1p * 10 + s2p];
      }
    }
    T2[idx] = S1 * acc + B1;
  }
  __syncthreads();

  // c2 stage: conv2 16x16 3x3 over f (y1 generated on the fly from T2),
  // then folded 16->1 3x3 conv over s. Chunked by f1-row.
  const float* w2r  = prm + 232;   // [tap][i][o]
  const float* W1r  = prm;         // [ds][i]
  const float* Av   = prm + 144;
  const float* Bpv  = prm + 160;
  const float* S2c2 = prm + 176;
  const float* B2c2 = prm + 192;
  float* resb = ws + (br ? OFF_RB : OFF_RA) + it * 10000;

  for (int g = 0; g < 10; ++g) {
    if (t < 1000) {
      const int lf = t / 100, s = t % 100;   // f = g*10+lf -> f1=g, f2=lf
      float acc[16];
      #pragma unroll
      for (int o = 0; o < 16; ++o) acc[o] = 0.f;
      #pragma unroll
      for (int du = 0; du < 3; ++du) {
        int f1p = g + du - 1;
        if ((unsigned)f1p >= 10u) continue;
        #pragma unroll
        for (int dv = 0; dv < 3; ++dv) {
          int f2p = lf + dv - 1;
          if ((unsigned)f2p >= 10u) continue;
          float t2v = T2[(f1p * 10 + f2p) * 100 + s];
          const int tap = du * 3 + dv;
          #pragma unroll
          for (int i = 0; i < 16; ++i) {
            float y1 = Av[i] * t2v + Bpv[i];
            y1 = y1 > 0.f ? y1 : 0.f;
            const float* wrow = w2r + tap * 256 + i * 16;
            #pragma unroll
            for (int o = 0; o < 16; ++o) acc[o] += wrow[o] * y1;
          }
        }
      }
      #pragma unroll
      for (int o = 0; o < 16; ++o) {
        float v = S2c2[o] * acc[o] + B2c2[o];
        Y2[(o * 10 + lf) * 100 + s] = (_Float16)(v > 0.f ? v : 0.f);
      }
    }
    __syncthreads();
    if (t < 1000) {
      const int lf = t / 100, s = t % 100;
      const int f = g * 10 + lf;
      const int s1i = s / 10, s2i = s % 10;
      float acc = Cf;
      #pragma unroll
      for (int dh = 0; dh < 3; ++dh) {
        int s1p = s1i + dh - 1;
        if ((unsigned)s1p >= 10u) continue;
        #pragma unroll
        for (int dw = 0; dw < 3; ++dw) {
          int s2p = s2i + dw - 1;
          if ((unsigned)s2p >= 10u) continue;
          const int sp2 = s1p * 10 + s2p;
          const int ds = dh * 3 + dw;
          #pragma unroll
          for (int i = 0; i < 16; ++i)
            acc += W1r[ds * 16 + i] * (float)Y2[(i * 10 + lf) * 100 + sp2];
        }
      }
      int pos = br ? (s * 100 + f) : (f * 100 + s);
      resb[pos] = acc;
    }
    __syncthreads();
  }
}

// ---------------------------------------------------------------------------
// per-item gaussian_normalize + softmax(/5) over each axis; attn sums
__global__ __launch_bounds__(128) void k_stats(float* __restrict__ ws)
{
  __shared__ float F[10000];
  __shared__ float mc[100], ic[100], rc[100];
  __shared__ float mr[100], ir[100], rr[100];
  const int it = blockIdx.x, t = threadIdx.x;
  const float* ra = ws + OFF_RA + it * 10000;
  const float* rb = ws + OFF_RB + it * 10000;
  for (int idx = t; idx < 10000; idx += 128) F[idx] = ra[idx] + rb[idx];
  __syncthreads();
  if (t < 100) {
    // column kl=t (over ij): corr_s normalization axis
    float s = 0.f;
    for (int ij = 0; ij < 100; ++ij) s += F[ij * 100 + t];
    float m = s * 0.01f;
    float ss = 0.f;
    for (int ij = 0; ij < 100; ++ij) { float d = F[ij * 100 + t] - m; ss += d * d; }
    float inv = 1.f / (sqrtf(ss * (1.f / 99.f) + 1e-5f) * 5.f);
    float den = 0.f;
    for (int ij = 0; ij < 100; ++ij) den += __expf((F[ij * 100 + t] - m) * inv);
    mc[t] = m; ic[t] = inv; rc[t] = 1.f / den;
    // row ij=t (over kl): corr_q normalization axis
    s = 0.f;
    for (int kl = 0; kl < 100; ++kl) s += F[t * 100 + kl];
    m = s * 0.01f;
    ss = 0.f;
    for (int kl = 0; kl < 100; ++kl) { float d = F[t * 100 + kl] - m; ss += d * d; }
    inv = 1.f / (sqrtf(ss * (1.f / 99.f) + 1e-5f) * 5.f);
    den = 0.f;
    for (int kl = 0; kl < 100; ++kl) den += __expf((F[t * 100 + kl] - m) * inv);
    mr[t] = m; ir[t] = inv; rr[t] = 1.f / den;
  }
  __syncthreads();
  if (t < 100) {
    float s = 0.f;
    for (int kl = 0; kl < 100; ++kl)
      s += __expf((F[t * 100 + kl] - mc[kl]) * ic[kl]) * rc[kl];
    ws[OFF_AS + it * 100 + t] = s;                    // attn_s[ij=t]
    float s2 = 0.f;
    for (int ij = 0; ij < 100; ++ij)
      s2 += __expf((F[ij * 100 + t] - mr[ij]) * ir[ij]) * rr[ij];
    ws[OFF_AQ + it * 100 + t] = s2;                   // attn_q[kl=t]
  }
}

// ---------------------------------------------------------------------------
// attention pooling + cosine similarity
__global__ __launch_bounds__(256) void k_sim(float* __restrict__ ws, float* __restrict__ out)
{
  __shared__ float asL[100], aqL[100];
  __shared__ float red[12];
  const int it = blockIdx.x, t = threadIdx.x;
  const int q = it / 5, n = it % 5;
  if (t < 100) { asL[t] = ws[OFF_AS + it * 100 + t]; aqL[t] = ws[OFF_AQ + it * 100 + t]; }
  __syncthreads();
  const float* sc = ws + OFF_SC + n * 64000;
  const float* qc = ws + OFF_QC + q * 64000;
  float dot = 0.f, na = 0.f, nb = 0.f;
  for (int c = t; c < 640; c += 256) {
    float sa = 0.f, qa = 0.f;
    for (int p = 0; p < 100; ++p) {
      sa += asL[p] * sc[c * 100 + p];
      qa += aqL[p] * qc[c * 100 + p];
    }
    sa *= 0.01f; qa *= 0.01f;
    dot += sa * qa; na += sa * sa; nb += qa * qa;
  }
  #pragma unroll
  for (int off = 32; off > 0; off >>= 1) {
    dot += __shfl_down(dot, off);
    na  += __shfl_down(na, off);
    nb  += __shfl_down(nb, off);
  }
  const int wid = t >> 6, lane = t & 63;
  if (lane == 0) { red[wid * 3 + 0] = dot; red[wid * 3 + 1] = na; red[wid * 3 + 2] = nb; }
  __syncthreads();
  if (t == 0) {
    dot = red[0] + red[3] + red[6] + red[9];
    na  = red[1] + red[4] + red[7] + red[10];
    nb  = red[2] + red[5] + red[8] + red[11];
    float ns = sqrtf(na); ns = ns > 1e-8f ? ns : 1e-8f;
    float nq2 = sqrtf(nb); nq2 = nq2 > 1e-8f ? nq2 : 1e-8f;
    out[it] = dot / (ns * nq2) * 5.f;   // /TEMPERATURE(0.2)
  }
}

// ---------------------------------------------------------------------------
extern "C" void kernel_launch(void* const* d_in, const int* in_sizes, int n_in,
                              void* d_out, int out_size, void* d_ws, size_t ws_size,
                              hipStream_t stream)
{
  (void)in_sizes; (void)n_in; (void)out_size; (void)ws_size;
  const float* spt    = (const float*)d_in[0];
  const float* qry    = (const float*)d_in[1];
  const float* w1x1   = (const float*)d_in[2];
  const float* bn1x1  = (const float*)d_in[3];
  const float* c1c2w  = (const float*)d_in[4];
  const float* c1bn2  = (const float*)d_in[5];
  const float* c1c1w  = (const float*)d_in[6];
  const float* c1bn1  = (const float*)d_in[7];
  const float* c1pj   = (const float*)d_in[8];
  const float* c1bnp  = (const float*)d_in[9];
  const float* c2c2w  = (const float*)d_in[10];
  const float* c2bn2  = (const float*)d_in[11];
  const float* c2c1w  = (const float*)d_in[12];
  const float* c2bn1  = (const float*)d_in[13];
  const float* c2pj   = (const float*)d_in[14];
  const float* c2bnp  = (const float*)d_in[15];
  float* ws  = (float*)d_ws;
  float* out = (float*)d_out;

  k_prep<<<1, 256, 0, stream>>>(c1c2w, c1bn2, c1c1w, c1bn1, c1pj, c1bnp,
                                c2c2w, c2bn2, c2c1w, c2bn1, c2pj, c2bnp,
                                ws + OFF_PRM);
  k_center<<<80, 128, 0, stream>>>(spt, qry, ws, out);
  k_feat<<<80, 512, 0, stream>>>(w1x1, bn1x1, ws);

  // 91.2 KB dynamic LDS (>64KB default cap) — opt in each call (idempotent)
  (void)hipFuncSetAttribute((const void*)k_cca,
                            hipFuncAttributeMaxDynamicSharedMemorySize, 91200);
  k_cca<<<NITEM * 2, 1024, 91200, stream>>>(ws);

  k_stats<<<NITEM, 128, 0, stream>>>(ws);
  k_sim<<<NITEM, 256, 0, stream>>>(ws, out);
}

// Round 2
// 2575.768 us; speedup vs baseline: 1.1518x; 1.1518x over previous
//
#include <hip/hip_runtime.h>

// ---------------------------------------------------------------------------
// CCALayer: sizes
//   spt (1,5,640,10,10)  qry (75,640,10,10)
//   Q=75, way=5, C=640, Cf=64, spatial P=100 (10x10), items = 375
// Output: sim (75,5) [375 floats] ++ qry_pooled (75,640) [48000 floats]
// ---------------------------------------------------------------------------

#define NQ    75
#define NWAY  5
#define NITEM 375

// ws layout (float offsets)
#define OFF_SC  0            // centered support   5*640*100   = 320000
#define OFF_QC  320000       // centered query    75*640*100   = 4800000
#define OFF_SF  5120000      // sf  5*64*100 = 32000
#define OFF_QF  5152000      // qf 75*64*100 = 480000
#define OFF_RA  5632000      // branch-A result 375*10000
#define OFF_RB  9382000      // branch-B result 375*10000
#define OFF_AS  13132000     // attn_s 375*100
#define OFF_AQ  13169500     // attn_q 375*100
#define OFF_PRM 13207000     // folded params (2536 floats)

// prm layout:
// [0..143]   W1eff  [ds][i]        (c2 conv1 (+bn1+proj+bnp) folded to 16->1)
// [144..159] A[i]   (c1 proj*bnp scale)
// [160..175] Bp[i]  (c1 proj*bnp shift)
// [176..191] S2c2[o], [192..207] B2c2[o]   (c2 bn2)
// [208..216] w2c1 (c1 conv over first dims), [217..225] w1c1 (c1 conv over second dims)
// [226] S2 [227] B2 [228] S1 [229] B1 [230] Cf
// [232..2535] w2r [tap][i][o]  (c2 conv2 weights repacked)

typedef _Float16 half8 __attribute__((ext_vector_type(8)));

__global__ __launch_bounds__(256) void k_prep(
    const float* __restrict__ c1c2w, const float* __restrict__ c1bn2,
    const float* __restrict__ c1c1w, const float* __restrict__ c1bn1,
    const float* __restrict__ c1pj,  const float* __restrict__ c1bnp,
    const float* __restrict__ c2c2w, const float* __restrict__ c2bn2,
    const float* __restrict__ c2c1w, const float* __restrict__ c2bn1,
    const float* __restrict__ c2pj,  const float* __restrict__ c2bnp,
    float* __restrict__ prm)
{
  const int t = threadIdx.x;
  const float eps = 1e-5f;

  // W1eff [ds][i]
  for (int idx = t; idx < 144; idx += 256) {
    int ds = idx / 16, i = idx % 16;
    float spv = c2bnp[0] / sqrtf(c2bnp[3] + eps);
    float acc = 0.f;
    for (int o = 0; o < 16; ++o) {
      float s1 = c2bn1[o] / sqrtf(c2bn1[48 + o] + eps);
      acc += c2pj[o] * s1 * c2c1w[(o * 16 + i) * 9 + ds];
    }
    prm[idx] = spv * acc;
  }
  // A, Bp (c1 proj folded with c1 bnp)
  for (int i = t; i < 16; i += 256) {
    float s = c1bnp[i] / sqrtf(c1bnp[48 + i] + eps);
    prm[144 + i] = s * c1pj[i];
    prm[160 + i] = c1bnp[16 + i] - c1bnp[32 + i] * s;
  }
  // c2 bn2
  for (int o = t; o < 16; o += 256) {
    float s = c2bn2[o] / sqrtf(c2bn2[48 + o] + eps);
    prm[176 + o] = s;
    prm[192 + o] = c2bn2[16 + o] - c2bn2[32 + o] * s;
  }
  // c1 conv kernels (9 taps each)
  for (int k = t; k < 9; k += 256) {
    prm[208 + k] = c1c2w[k];
    prm[217 + k] = c1c1w[k];
  }
  if (t == 0) {
    float S2 = c1bn2[0] / sqrtf(c1bn2[3] + eps);
    prm[226] = S2;
    prm[227] = c1bn2[1] - c1bn2[2] * S2;
    float S1 = c1bn1[0] / sqrtf(c1bn1[3] + eps);
    prm[228] = S1;
    prm[229] = c1bn1[1] - c1bn1[2] * S1;
    float spv = c2bnp[0] / sqrtf(c2bnp[3] + eps);
    float k0 = 0.f;
    for (int o = 0; o < 16; ++o) {
      float s1 = c2bn1[o] / sqrtf(c2bn1[48 + o] + eps);
      k0 += c2pj[o] * (c2bn1[16 + o] - c2bn1[32 + o] * s1);
    }
    prm[230] = spv * (k0 - c2bnp[2]) + c2bnp[1];
    prm[231] = 0.f;
  }
  // repack c2 conv2 weights: w2r[tap][i][o]
  for (int idx = t; idx < 2304; idx += 256) {
    int tap = idx >> 8, rem = idx & 255, i = rem >> 4, o = rem & 15;
    prm[232 + idx] = c2c2w[(o * 16 + i) * 9 + tap];
  }
}

// ---------------------------------------------------------------------------
// center features (subtract channel mean); also emit qry_pooled
__global__ __launch_bounds__(128) void k_center(
    const float* __restrict__ spt, const float* __restrict__ qry,
    float* __restrict__ ws, float* __restrict__ out)
{
  const int b = blockIdx.x, t = threadIdx.x;
  const float* src = (b < 5) ? spt + b * 64000 : qry + (b - 5) * 64000;
  float* dst = (b < 5) ? ws + OFF_SC + b * 64000 : ws + OFF_QC + (b - 5) * 64000;
  __shared__ float mp[100];
  __shared__ float msum;
  if (t < 100) {
    float s = 0.f;
    for (int c = 0; c < 640; ++c) s += src[c * 100 + t];
    mp[t] = s * (1.f / 640.f);
  }
  __syncthreads();
  if (t == 0) { float s = 0.f; for (int p = 0; p < 100; ++p) s += mp[p]; msum = s; }
  for (int idx = t; idx < 64000; idx += 128) dst[idx] = src[idx] - mp[idx % 100];
  __syncthreads();
  if (b >= 5) {
    for (int c = t; c < 640; c += 128) {
      float s = 0.f;
      for (int p = 0; p < 100; ++p) s += src[c * 100 + p];
      out[375 + (b - 5) * 640 + c] = (s - msum) * 0.01f;
    }
  }
}

// ---------------------------------------------------------------------------
// 1x1 conv 640->64 + BN + relu + per-position L2 normalize
__global__ __launch_bounds__(512) void k_feat(
    const float* __restrict__ w1x1, const float* __restrict__ bn1x1,
    float* __restrict__ ws)
{
  const int b = blockIdx.x, t = threadIdx.x;
  const float* src = (b < 5) ? ws + OFF_SC + b * 64000 : ws + OFF_QC + (b - 5) * 64000;
  float* dst = (b < 5) ? ws + OFF_SF + b * 6400 : ws + OFF_QF + (b - 5) * 6400;

  __shared__ float xch[6400];   // [64 c][100 p] ; reused as fL[64][100]
  __shared__ float wch[4096];   // [64 o][64 c]
  __shared__ float rn[100];

  float acc[16];
  #pragma unroll
  for (int k = 0; k < 16; ++k) acc[k] = 0.f;

  const int ot = t / 25, pt = t % 25;      // valid tiles: t < 400
  const int o0 = ot * 4, p0 = pt * 4;

  for (int cc = 0; cc < 10; ++cc) {
    __syncthreads();
    for (int idx = t; idx < 6400; idx += 512) xch[idx] = src[cc * 6400 + idx];
    for (int idx = t; idx < 4096; idx += 512) {
      int o = idx >> 6, c = idx & 63;
      wch[idx] = w1x1[o * 640 + cc * 64 + c];
    }
    __syncthreads();
    if (t < 400) {
      for (int c = 0; c < 64; ++c) {
        float xv[4], wv[4];
        #pragma unroll
        for (int k = 0; k < 4; ++k) xv[k] = xch[c * 100 + p0 + k];
        #pragma unroll
        for (int j = 0; j < 4; ++j) wv[j] = wch[(o0 + j) * 64 + c];
        #pragma unroll
        for (int j = 0; j < 4; ++j)
          #pragma unroll
          for (int k = 0; k < 4; ++k) acc[j * 4 + k] += wv[j] * xv[k];
      }
    }
  }
  __syncthreads();
  float* fL = xch;
  if (t < 400) {
    #pragma unroll
    for (int j = 0; j < 4; ++j) {
      int o = o0 + j;
      float scv = bn1x1[o] / sqrtf(bn1x1[192 + o] + 1e-5f);
      float shv = bn1x1[64 + o] - bn1x1[128 + o] * scv;
      #pragma unroll
      for (int k = 0; k < 4; ++k) {
        float v = scv * acc[j * 4 + k] + shv;
        fL[o * 100 + p0 + k] = v > 0.f ? v : 0.f;
      }
    }
  }
  __syncthreads();
  if (t < 100) {
    float s = 0.f;
    for (int o = 0; o < 64; ++o) { float v = fL[o * 100 + t]; s += v * v; }
    float nr = sqrtf(s);
    rn[t] = 1.f / (nr > 1e-8f ? nr : 1e-8f);
  }
  __syncthreads();
  for (int idx = t; idx < 6400; idx += 512) dst[idx] = fL[idx] * rn[idx % 100];
}

// ---------------------------------------------------------------------------
// Fused corr + cca branch. grid = 375 items x 2 branches.
// branch 0: f = uv(ij), s = hw(kl);  branch 1: f = hw, s = uv.
// LDS phases: A) CORR(40000) + sf(25600)+qf(25600)
//             B) T1(40000 at +40000), T2 overwrites CORR
//             C) Y2 fp16 [20 f][100 s][16 i] = 64000 B at +40000
// total 104000 B dynamic.
// __launch_bounds__(1024, 4): LDS caps us at 1 block/CU anyway (4 waves/EU),
// so let the allocator use 128 VGPRs -> no scratch spills (R1: 1.4GB spill HBM)
__global__ __launch_bounds__(1024, 4) void k_cca(float* __restrict__ ws)
{
  extern __shared__ char smem[];
  float* CORR = (float*)(smem);
  float* sfL  = (float*)(smem + 40000);
  float* qfL  = (float*)(smem + 40000 + 25600);
  float* T1   = (float*)(smem + 40000);
  half8* Y2v  = (half8*)(smem + 40000);   // [(fl*100+s)*2 + hi/lo]

  const float* prm = ws + OFF_PRM;
  const int bid = blockIdx.x;
  const int it = bid >> 1, br = bid & 1;
  const int q = it / 5, n = it % 5;
  const int t = threadIdx.x;

  const float* sf = ws + OFF_SF + n * 6400;
  const float* qf = ws + OFF_QF + q * 6400;

  for (int idx = t; idx < 6400; idx += 1024) {
    sfL[idx] = sf[idx];
    qfL[idx] = qf[idx];
  }
  __syncthreads();

  // corr in generic layout [f*100+s]
  for (int idx = t; idx < 10000; idx += 1024) {
    int a = idx / 100, b2 = idx % 100;
    int ij = br ? b2 : a;
    int kl = br ? a : b2;
    float acc = 0.f;
    #pragma unroll 8
    for (int c = 0; c < 64; ++c) acc += sfL[c * 100 + ij] * qfL[c * 100 + kl];
    CORR[idx] = acc;
  }
  __syncthreads();

  const float S2 = prm[226], B2 = prm[227], S1 = prm[228], B1 = prm[229], Cf = prm[230];

  // c1 first conv (3x3 over f dims) + bn2 + relu -> T1
  for (int idx = t; idx < 10000; idx += 1024) {
    int f = idx / 100, s = idx % 100;
    int f1 = f / 10, f2 = f % 10;
    float acc = 0.f;
    #pragma unroll
    for (int du = 0; du < 3; ++du) {
      int f1p = f1 + du - 1;
      if ((unsigned)f1p >= 10u) continue;
      #pragma unroll
      for (int dv = 0; dv < 3; ++dv) {
        int f2p = f2 + dv - 1;
        if ((unsigned)f2p >= 10u) continue;
        acc += prm[208 + du * 3 + dv] * CORR[(f1p * 10 + f2p) * 100 + s];
      }
    }
    float v = S2 * acc + B2;
    T1[idx] = v > 0.f ? v : 0.f;
  }
  __syncthreads();

  // c1 second conv (3x3 over s dims) + bn1 -> T2 (overwrites CORR)
  float* T2 = CORR;
  for (int idx = t; idx < 10000; idx += 1024) {
    int f = idx / 100, s = idx % 100;
    int s1i = s / 10, s2i = s % 10;
    float acc = 0.f;
    #pragma unroll
    for (int dh = 0; dh < 3; ++dh) {
      int s1p = s1i + dh - 1;
      if ((unsigned)s1p >= 10u) continue;
      #pragma unroll
      for (int dw = 0; dw < 3; ++dw) {
        int s2p = s2i + dw - 1;
        if ((unsigned)s2p >= 10u) continue;
        acc += prm[217 + dh * 3 + dw] * T1[f * 100 + s1p * 10 + s2p];
      }
    }
    T2[idx] = S1 * acc + B1;
  }
  __syncthreads();

  // c2 stage: conv2 16x16 3x3 over f (y1 = relu(A*t2+B) on the fly),
  // then folded 16->1 3x3 conv over s. 2 f-rows (2000 pts) per g-iter,
  // 2 consecutive-s points per thread (acc[2][16] in VGPRs).
  const float* w2r  = prm + 232;   // [tap][i][o]
  const float* W1r  = prm;         // [ds][i]
  const float* Av   = prm + 144;
  const float* Bpv  = prm + 160;
  const float* S2c2 = prm + 176;
  const float* B2c2 = prm + 192;
  float* resb = ws + (br ? OFF_RB : OFF_RA) + it * 10000;

  const int fl = t / 50;            // 0..19 (for t<1000)
  const int s0 = (t % 50) * 2;      // even s
  const int f2 = fl % 10;
  const int s1i0 = s0 / 10, s2i0 = s0 % 10;

  for (int g = 0; g < 5; ++g) {
    if (t < 1000) {
      const int f1 = 2 * g + fl / 10;
      float acc0[16], acc1[16];
      #pragma unroll
      for (int o = 0; o < 16; ++o) { acc0[o] = 0.f; acc1[o] = 0.f; }
      #pragma unroll
      for (int du = 0; du < 3; ++du) {
        int f1p = f1 + du - 1;
        if ((unsigned)f1p >= 10u) continue;
        #pragma unroll
        for (int dv = 0; dv < 3; ++dv) {
          int f2p = f2 + dv - 1;
          if ((unsigned)f2p >= 10u) continue;
          const float* t2p = T2 + (f1p * 10 + f2p) * 100 + s0;
          float t2v0 = t2p[0], t2v1 = t2p[1];
          const int tap = du * 3 + dv;
          const float* wt = w2r + tap * 256;
          #pragma unroll
          for (int i = 0; i < 16; ++i) {
            float y10 = Av[i] * t2v0 + Bpv[i]; y10 = y10 > 0.f ? y10 : 0.f;
            float y11 = Av[i] * t2v1 + Bpv[i]; y11 = y11 > 0.f ? y11 : 0.f;
            const float* wrow = wt + i * 16;
            #pragma unroll
            for (int o = 0; o < 16; ++o) {
              acc0[o] += wrow[o] * y10;
              acc1[o] += wrow[o] * y11;
            }
          }
        }
      }
      // write Y2[fl][s][o] as fp16, 16-B vectors
      half8 v0a, v0b, v1a, v1b;
      #pragma unroll
      for (int o = 0; o < 8; ++o) {
        float w0 = S2c2[o] * acc0[o] + B2c2[o];
        float w1 = S2c2[o + 8] * acc0[o + 8] + B2c2[o + 8];
        float x0 = S2c2[o] * acc1[o] + B2c2[o];
        float x1 = S2c2[o + 8] * acc1[o + 8] + B2c2[o + 8];
        v0a[o] = (_Float16)(w0 > 0.f ? w0 : 0.f);
        v0b[o] = (_Float16)(w1 > 0.f ? w1 : 0.f);
        v1a[o] = (_Float16)(x0 > 0.f ? x0 : 0.f);
        v1b[o] = (_Float16)(x1 > 0.f ? x1 : 0.f);
      }
      const int base = (fl * 100 + s0) * 2;
      Y2v[base]     = v0a;
      Y2v[base + 1] = v0b;
      Y2v[base + 2] = v1a;
      Y2v[base + 3] = v1b;
    }
    __syncthreads();
    if (t < 1000) {
      const int f = 20 * g + fl;
      float accA = Cf, accB = Cf;
      #pragma unroll
      for (int dh = 0; dh < 3; ++dh) {
        int s1p = s1i0 + dh - 1;
        bool okA = (unsigned)s1p < 10u;
        if (!okA) continue;          // same row for both points (s0, s0+1)
        #pragma unroll
        for (int dw = 0; dw < 3; ++dw) {
          // point A: s2 = s2i0 + dw - 1 ; point B: s2 = s2i0 + dw
          int s2pA = s2i0 + dw - 1;
          int s2pB = s2i0 + dw;        // == s2pA+1
          const int ds = dh * 3 + dw;
          if ((unsigned)s2pA < 10u) {
            const int sp2 = s1p * 10 + s2pA;
            half8 a = Y2v[(fl * 100 + sp2) * 2];
            half8 b = Y2v[(fl * 100 + sp2) * 2 + 1];
            #pragma unroll
            for (int i = 0; i < 8; ++i) {
              accA += W1r[ds * 16 + i] * (float)a[i];
              accA += W1r[ds * 16 + 8 + i] * (float)b[i];
            }
          }
          if ((unsigned)s2pB < 10u) {
            const int sp2 = s1p * 10 + s2pB;
            half8 a = Y2v[(fl * 100 + sp2) * 2];
            half8 b = Y2v[(fl * 100 + sp2) * 2 + 1];
            #pragma unroll
            for (int i = 0; i < 8; ++i) {
              accB += W1r[ds * 16 + i] * (float)a[i];
              accB += W1r[ds * 16 + 8 + i] * (float)b[i];
            }
          }
        }
      }
      int posA = br ? (s0 * 100 + f) : (f * 100 + s0);
      int posB = br ? ((s0 + 1) * 100 + f) : (f * 100 + s0 + 1);
      resb[posA] = accA;
      resb[posB] = accB;
    }
    __syncthreads();
  }
}

// ---------------------------------------------------------------------------
// per-item gaussian_normalize + softmax(/5) over each axis; attn sums
__global__ __launch_bounds__(128) void k_stats(float* __restrict__ ws)
{
  __shared__ float F[10000];
  __shared__ float mc[100], ic[100], rc[100];
  __shared__ float mr[100], ir[100], rr[100];
  const int it = blockIdx.x, t = threadIdx.x;
  const float* ra = ws + OFF_RA + it * 10000;
  const float* rb = ws + OFF_RB + it * 10000;
  for (int idx = t; idx < 10000; idx += 128) F[idx] = ra[idx] + rb[idx];
  __syncthreads();
  if (t < 100) {
    float s = 0.f;
    for (int ij = 0; ij < 100; ++ij) s += F[ij * 100 + t];
    float m = s * 0.01f;
    float ss = 0.f;
    for (int ij = 0; ij < 100; ++ij) { float d = F[ij * 100 + t] - m; ss += d * d; }
    float inv = 1.f / (sqrtf(ss * (1.f / 99.f) + 1e-5f) * 5.f);
    float den = 0.f;
    for (int ij = 0; ij < 100; ++ij) den += __expf((F[ij * 100 + t] - m) * inv);
    mc[t] = m; ic[t] = inv; rc[t] = 1.f / den;
    s = 0.f;
    for (int kl = 0; kl < 100; ++kl) s += F[t * 100 + kl];
    m = s * 0.01f;
    ss = 0.f;
    for (int kl = 0; kl < 100; ++kl) { float d = F[t * 100 + kl] - m; ss += d * d; }
    inv = 1.f / (sqrtf(ss * (1.f / 99.f) + 1e-5f) * 5.f);
    den = 0.f;
    for (int kl = 0; kl < 100; ++kl) den += __expf((F[t * 100 + kl] - m) * inv);
    mr[t] = m; ir[t] = inv; rr[t] = 1.f / den;
  }
  __syncthreads();
  if (t < 100) {
    float s = 0.f;
    for (int kl = 0; kl < 100; ++kl)
      s += __expf((F[t * 100 + kl] - mc[kl]) * ic[kl]) * rc[kl];
    ws[OFF_AS + it * 100 + t] = s;                    // attn_s[ij=t]
    float s2 = 0.f;
    for (int ij = 0; ij < 100; ++ij)
      s2 += __expf((F[ij * 100 + t] - mr[ij]) * ir[ij]) * rr[ij];
    ws[OFF_AQ + it * 100 + t] = s2;                   // attn_q[kl=t]
  }
}

// ---------------------------------------------------------------------------
// attention pooling + cosine similarity
__global__ __launch_bounds__(256) void k_sim(float* __restrict__ ws, float* __restrict__ out)
{
  __shared__ float asL[100], aqL[100];
  __shared__ float red[12];
  const int it = blockIdx.x, t = threadIdx.x;
  const int q = it / 5, n = it % 5;
  if (t < 100) { asL[t] = ws[OFF_AS + it * 100 + t]; aqL[t] = ws[OFF_AQ + it * 100 + t]; }
  __syncthreads();
  const float* sc = ws + OFF_SC + n * 64000;
  const float* qc = ws + OFF_QC + q * 64000;
  float dot = 0.f, na = 0.f, nb = 0.f;
  for (int c = t; c < 640; c += 256) {
    float sa = 0.f, qa = 0.f;
    for (int p = 0; p < 100; ++p) {
      sa += asL[p] * sc[c * 100 + p];
      qa += aqL[p] * qc[c * 100 + p];
    }
    sa *= 0.01f; qa *= 0.01f;
    dot += sa * qa; na += sa * sa; nb += qa * qa;
  }
  #pragma unroll
  for (int off = 32; off > 0; off >>= 1) {
    dot += __shfl_down(dot, off);
    na  += __shfl_down(na, off);
    nb  += __shfl_down(nb, off);
  }
  const int wid = t >> 6, lane = t & 63;
  if (lane == 0) { red[wid * 3 + 0] = dot; red[wid * 3 + 1] = na; red[wid * 3 + 2] = nb; }
  __syncthreads();
  if (t == 0) {
    dot = red[0] + red[3] + red[6] + red[9];
    na  = red[1] + red[4] + red[7] + red[10];
    nb  = red[2] + red[5] + red[8] + red[11];
    float ns = sqrtf(na); ns = ns > 1e-8f ? ns : 1e-8f;
    float nq2 = sqrtf(nb); nq2 = nq2 > 1e-8f ? nq2 : 1e-8f;
    out[it] = dot / (ns * nq2) * 5.f;   // /TEMPERATURE(0.2)
  }
}

// ---------------------------------------------------------------------------
extern "C" void kernel_launch(void* const* d_in, const int* in_sizes, int n_in,
                              void* d_out, int out_size, void* d_ws, size_t ws_size,
                              hipStream_t stream)
{
  (void)in_sizes; (void)n_in; (void)out_size; (void)ws_size;
  const float* spt    = (const float*)d_in[0];
  const float* qry    = (const float*)d_in[1];
  const float* w1x1   = (const float*)d_in[2];
  const float* bn1x1  = (const float*)d_in[3];
  const float* c1c2w  = (const float*)d_in[4];
  const float* c1bn2  = (const float*)d_in[5];
  const float* c1c1w  = (const float*)d_in[6];
  const float* c1bn1  = (const float*)d_in[7];
  const float* c1pj   = (const float*)d_in[8];
  const float* c1bnp  = (const float*)d_in[9];
  const float* c2c2w  = (const float*)d_in[10];
  const float* c2bn2  = (const float*)d_in[11];
  const float* c2c1w  = (const float*)d_in[12];
  const float* c2bn1  = (const float*)d_in[13];
  const float* c2pj   = (const float*)d_in[14];
  const float* c2bnp  = (const float*)d_in[15];
  float* ws  = (float*)d_ws;
  float* out = (float*)d_out;

  k_prep<<<1, 256, 0, stream>>>(c1c2w, c1bn2, c1c1w, c1bn1, c1pj, c1bnp,
                                c2c2w, c2bn2, c2c1w, c2bn1, c2pj, c2bnp,
                                ws + OFF_PRM);
  k_center<<<80, 128, 0, stream>>>(spt, qry, ws, out);
  k_feat<<<80, 512, 0, stream>>>(w1x1, bn1x1, ws);

  // 104000 B dynamic LDS (>64KB default cap) — opt in each call (idempotent)
  (void)hipFuncSetAttribute((const void*)k_cca,
                            hipFuncAttributeMaxDynamicSharedMemorySize, 104000);
  k_cca<<<NITEM * 2, 1024, 104000, stream>>>(ws);

  k_stats<<<NITEM, 128, 0, stream>>>(ws);
  k_sim<<<NITEM, 256, 0, stream>>>(ws, out);
}

// Round 3
// 917.484 us; speedup vs baseline: 3.2336x; 2.8074x over previous
//
#include <hip/hip_runtime.h>

// ---------------------------------------------------------------------------
// CCALayer: spt (1,5,640,10,10)  qry (75,640,10,10)
// Q=75, way=5, C=640, Cf=64, P=100 (10x10), items=375
// Output: sim (75,5) [375] ++ qry_pooled (75,640) [48000]
// ---------------------------------------------------------------------------

#define NITEM 375

// ws layout (float offsets)
#define OFF_SC  0            // centered support   5*640*100
#define OFF_QC  320000       // centered query    75*640*100
#define OFF_SF  5120000      // sf  5*64*100
#define OFF_QF  5152000      // qf 75*64*100
#define OFF_RA  5632000      // branch-A result 375*10000
#define OFF_RB  9382000      // branch-B result 375*10000
#define OFF_AS  13132000     // attn_s 375*100
#define OFF_AQ  13169500     // attn_q 375*100
#define OFF_PRM 13207000     // folded params

// prm layout (floats):
// [0..143] W1eff[ds][i]; [144..159] Av; [160..175] Bp
// [176..191] S2c2; [192..207] B2c2
// [208..216] w2c1; [217..225] w1c1
// [226] S2 [227] B2 [228] S1 [229] B1 [230] Cf
// PK2 (conv2 A-frags, 2560 fp16) at floats [232,1512)
// PK1 (conv1eff A-frags, 2560 fp16) at floats [1512,2792)
#define PK2F 232
#define PK1F 1512

typedef float f4v __attribute__((ext_vector_type(4)));
typedef float f32x4 __attribute__((ext_vector_type(4)));
typedef _Float16 half8v __attribute__((ext_vector_type(8)));

__device__ __forceinline__ unsigned int pack2h(float a, float b) {
  union { _Float16 h[2]; unsigned int u; } cv;
  cv.h[0] = (_Float16)a; cv.h[1] = (_Float16)b;
  return cv.u;
}

// ---------------------------------------------------------------------------
__global__ __launch_bounds__(256) void k_prep(
    const float* __restrict__ c1c2w, const float* __restrict__ c1bn2,
    const float* __restrict__ c1c1w, const float* __restrict__ c1bn1,
    const float* __restrict__ c1pj,  const float* __restrict__ c1bnp,
    const float* __restrict__ c2c2w, const float* __restrict__ c2bn2,
    const float* __restrict__ c2c1w, const float* __restrict__ c2bn1,
    const float* __restrict__ c2pj,  const float* __restrict__ c2bnp,
    float* __restrict__ prm)
{
  const int t = threadIdx.x;
  const float eps = 1e-5f;

  // W1eff[ds][i]: c2 conv1 + bn1 + proj + bnp folded 16->1
  for (int idx = t; idx < 144; idx += 256) {
    int ds = idx / 16, i = idx % 16;
    float spv = c2bnp[0] / sqrtf(c2bnp[3] + eps);
    float acc = 0.f;
    for (int o = 0; o < 16; ++o) {
      float s1 = c2bn1[o] / sqrtf(c2bn1[48 + o] + eps);
      acc += c2pj[o] * s1 * c2c1w[(o * 16 + i) * 9 + ds];
    }
    prm[idx] = spv * acc;
  }
  for (int i = t; i < 16; i += 256) {
    float s = c1bnp[i] / sqrtf(c1bnp[48 + i] + eps);
    prm[144 + i] = s * c1pj[i];
    prm[160 + i] = c1bnp[16 + i] - c1bnp[32 + i] * s;
  }
  for (int o = t; o < 16; o += 256) {
    float s = c2bn2[o] / sqrtf(c2bn2[48 + o] + eps);
    prm[176 + o] = s;
    prm[192 + o] = c2bn2[16 + o] - c2bn2[32 + o] * s;
  }
  for (int k = t; k < 9; k += 256) {
    prm[208 + k] = c1c2w[k];
    prm[217 + k] = c1c1w[k];
  }
  if (t == 0) {
    float S2 = c1bn2[0] / sqrtf(c1bn2[3] + eps);
    prm[226] = S2;
    prm[227] = c1bn2[1] - c1bn2[2] * S2;
    float S1 = c1bn1[0] / sqrtf(c1bn1[3] + eps);
    prm[228] = S1;
    prm[229] = c1bn1[1] - c1bn1[2] * S1;
    float spv = c2bnp[0] / sqrtf(c2bnp[3] + eps);
    float k0 = 0.f;
    for (int o = 0; o < 16; ++o) {
      float s1 = c2bn1[o] / sqrtf(c2bn1[48 + o] + eps);
      k0 += c2pj[o] * (c2bn1[16 + o] - c2bn1[32 + o] * s1);
    }
    prm[230] = spv * (k0 - c2bnp[2]) + c2bnp[1];
    prm[231] = 0.f;
  }
  __syncthreads();

  // PK2: conv2 A-fragments. A[m=o=lane&15][k=quad*8+j], tap=2c+(quad>>1),
  // i=(quad&1)*8+j. tap 9 = zero pad.
  _Float16* pk2 = (_Float16*)(prm + PK2F);
  for (int idx = t; idx < 2560; idx += 256) {
    int c = idx >> 9, rem = idx & 511;
    int ln = rem >> 3, j = rem & 7;
    int o = ln & 15, qq = ln >> 4;
    int tap = 2 * c + (qq >> 1);
    int i = (qq & 1) * 8 + j;
    float v = (tap < 9) ? c2c2w[(o * 16 + i) * 9 + tap] : 0.f;
    pk2[idx] = (_Float16)v;
  }
  // PK1: conv1-eff A-fragments (row m=0 only = W1eff, rest 0)
  _Float16* pk1 = (_Float16*)(prm + PK1F);
  for (int idx = t; idx < 2560; idx += 256) {
    int c = idx >> 9, rem = idx & 511;
    int ln = rem >> 3, j = rem & 7;
    int m = ln & 15, qq = ln >> 4;
    int k = c * 32 + qq * 8 + j;
    int tp = k >> 4, i = k & 15;
    float v = (m == 0 && tp < 9) ? prm[tp * 16 + i] : 0.f;
    pk1[idx] = (_Float16)v;
  }
}

// ---------------------------------------------------------------------------
// center features + qry_pooled
__global__ __launch_bounds__(256) void k_center(
    const float* __restrict__ spt, const float* __restrict__ qry,
    float* __restrict__ ws, float* __restrict__ out)
{
  const int b = blockIdx.x, t = threadIdx.x;
  const float* src = (b < 5) ? spt + b * 64000 : qry + (b - 5) * 64000;
  float* dst = (b < 5) ? ws + OFF_SC + b * 64000 : ws + OFF_QC + (b - 5) * 64000;
  __shared__ float mpp[2][100];
  __shared__ __align__(16) float mp[100];
  __shared__ float msum;
  if (t < 200) {
    int hh = t / 100, p = t - hh * 100;
    float s = 0.f;
    for (int c = hh; c < 640; c += 2) s += src[c * 100 + p];
    mpp[hh][p] = s;
  }
  __syncthreads();
  if (t < 100) mp[t] = (mpp[0][t] + mpp[1][t]) * (1.f / 640.f);
  __syncthreads();
  if (t == 0) { float s = 0.f; for (int p = 0; p < 100; ++p) s += mp[p]; msum = s; }
  const f4v* s4 = (const f4v*)src;
  f4v* d4 = (f4v*)dst;
  for (int idx = t; idx < 16000; idx += 256) {
    const f4v m4 = *(const f4v*)(mp + (idx % 25) * 4);
    f4v x = s4[idx];
    #pragma unroll
    for (int e = 0; e < 4; ++e) x[e] = x[e] - m4[e];
    d4[idx] = x;
  }
  __syncthreads();
  if (b >= 5) {
    for (int c = t; c < 640; c += 256) {
      float s = 0.f;
      for (int p = 0; p < 100; ++p) s += src[c * 100 + p];
      out[375 + (b - 5) * 640 + c] = (s - msum) * 0.01f;
    }
  }
}

// ---------------------------------------------------------------------------
// 1x1 conv 640->64 + BN + relu + per-position L2 normalize
__global__ __launch_bounds__(512) void k_feat(
    const float* __restrict__ w1x1, const float* __restrict__ bn1x1,
    float* __restrict__ ws)
{
  const int b = blockIdx.x, t = threadIdx.x;
  const float* src = (b < 5) ? ws + OFF_SC + b * 64000 : ws + OFF_QC + (b - 5) * 64000;
  float* dst = (b < 5) ? ws + OFF_SF + b * 6400 : ws + OFF_QF + (b - 5) * 6400;

  __shared__ float xch[6400];
  __shared__ float wch[4096];
  __shared__ float rn[100];

  float acc[16];
  #pragma unroll
  for (int k = 0; k < 16; ++k) acc[k] = 0.f;

  const int ot = t / 25, pt = t % 25;
  const int o0 = ot * 4, p0 = pt * 4;

  for (int cc = 0; cc < 10; ++cc) {
    __syncthreads();
    for (int idx = t; idx < 6400; idx += 512) xch[idx] = src[cc * 6400 + idx];
    for (int idx = t; idx < 4096; idx += 512) {
      int o = idx >> 6, c = idx & 63;
      wch[idx] = w1x1[o * 640 + cc * 64 + c];
    }
    __syncthreads();
    if (t < 400) {
      for (int c = 0; c < 64; ++c) {
        float xv[4], wv[4];
        #pragma unroll
        for (int k = 0; k < 4; ++k) xv[k] = xch[c * 100 + p0 + k];
        #pragma unroll
        for (int j = 0; j < 4; ++j) wv[j] = wch[(o0 + j) * 64 + c];
        #pragma unroll
        for (int j = 0; j < 4; ++j)
          #pragma unroll
          for (int k = 0; k < 4; ++k) acc[j * 4 + k] += wv[j] * xv[k];
      }
    }
  }
  __syncthreads();
  float* fL = xch;
  if (t < 400) {
    #pragma unroll
    for (int j = 0; j < 4; ++j) {
      int o = o0 + j;
      float scv = bn1x1[o] / sqrtf(bn1x1[192 + o] + 1e-5f);
      float shv = bn1x1[64 + o] - bn1x1[128 + o] * scv;
      #pragma unroll
      for (int k = 0; k < 4; ++k) {
        float v = scv * acc[j * 4 + k] + shv;
        fL[o * 100 + p0 + k] = v > 0.f ? v : 0.f;
      }
    }
  }
  __syncthreads();
  if (t < 100) {
    float s = 0.f;
    for (int o = 0; o < 64; ++o) { float v = fL[o * 100 + t]; s += v * v; }
    float nr = sqrtf(s);
    rn[t] = 1.f / (nr > 1e-8f ? nr : 1e-8f);
  }
  __syncthreads();
  for (int idx = t; idx < 6400; idx += 512) dst[idx] = fL[idx] * rn[idx % 100];
}

// ---------------------------------------------------------------------------
// Fused corr + cca branch with MFMA c2 stage. grid = 375 items x 2 branches.
// LDS: [0,20000)       T2 fp16
//      [20000,60000)   CORR fp32 (phase A/B)
//      [60000,111200)  sf+qf -> T1 (40 KB)
//      [20000,148000)  Y2 window fp16 [100 f][40 sl][16 o] (phase C)
__global__ __launch_bounds__(1024) __attribute__((amdgpu_waves_per_eu(4, 4)))
void k_cca(float* __restrict__ ws)
{
  extern __shared__ char smem[];
  _Float16* T2h = (_Float16*)smem;
  float* CORR = (float*)(smem + 20000);
  float* sfL  = (float*)(smem + 60000);
  float* qfL  = (float*)(smem + 85600);
  float* T1   = (float*)(smem + 60000);
  _Float16* Y2w = (_Float16*)(smem + 20000);

  const float* prm = ws + OFF_PRM;
  const int bid = blockIdx.x;
  const int it = bid >> 1, br = bid & 1;
  const int q = it / 5, n = it % 5;
  const int t = threadIdx.x;
  const int lane = t & 63, wv = t >> 6;
  const int n0 = lane & 15, qd = lane >> 4, qh = lane >> 5;
  const int i0 = (qd & 1) * 8;

  // per-lane constants (registers; weights stay resident -> no re-reads)
  float avj[8], bpj[8];
  #pragma unroll
  for (int j = 0; j < 8; ++j) { avj[j] = prm[144 + i0 + j]; bpj[j] = prm[160 + i0 + j]; }
  float sc2[4], bc2[4];
  #pragma unroll
  for (int r = 0; r < 4; ++r) { sc2[r] = prm[176 + qd * 4 + r]; bc2[r] = prm[192 + qd * 4 + r]; }
  const _Float16* pk2 = (const _Float16*)(prm + PK2F);
  const _Float16* pk1 = (const _Float16*)(prm + PK1F);
  half8v A2[5], A1[5];
  #pragma unroll
  for (int c = 0; c < 5; ++c) {
    A2[c] = *(const half8v*)(pk2 + c * 512 + lane * 8);
    A1[c] = *(const half8v*)(pk1 + c * 512 + lane * 8);
  }

  // stage sf/qf
  {
    const f4v* sf4 = (const f4v*)(ws + OFF_SF + n * 6400);
    const f4v* qf4 = (const f4v*)(ws + OFF_QF + q * 6400);
    f4v* sL4 = (f4v*)sfL; f4v* qL4 = (f4v*)qfL;
    for (int idx = t; idx < 1600; idx += 1024) { sL4[idx] = sf4[idx]; qL4[idx] = qf4[idx]; }
  }
  __syncthreads();

  // corr (4x4 register tile, b128 LDS loads). Generic layout CORR[f*100+s].
  if (t < 625) {
    const int ij0 = (t / 25) * 4, kl0 = (t % 25) * 4;
    f4v acc4[4];
    #pragma unroll
    for (int jj = 0; jj < 4; ++jj) { acc4[jj][0]=0.f; acc4[jj][1]=0.f; acc4[jj][2]=0.f; acc4[jj][3]=0.f; }
    for (int c = 0; c < 64; ++c) {
      f4v sv = *(const f4v*)(sfL + c * 100 + ij0);
      f4v qv = *(const f4v*)(qfL + c * 100 + kl0);
      #pragma unroll
      for (int jj = 0; jj < 4; ++jj)
        #pragma unroll
        for (int e = 0; e < 4; ++e) acc4[jj][e] += sv[jj] * qv[e];
    }
    if (br == 0) {
      #pragma unroll
      for (int jj = 0; jj < 4; ++jj) *(f4v*)(CORR + (ij0 + jj) * 100 + kl0) = acc4[jj];
    } else {
      #pragma unroll
      for (int kk = 0; kk < 4; ++kk) {
        f4v tr;
        #pragma unroll
        for (int jj = 0; jj < 4; ++jj) tr[jj] = acc4[jj][kk];
        *(f4v*)(CORR + (kl0 + kk) * 100 + ij0) = tr;
      }
    }
  }
  __syncthreads();

  const float S2 = prm[226], B2 = prm[227], S1 = prm[228], B1 = prm[229];

  // c1 first conv (3x3 over f) + bn2 + relu -> T1 (float4 over s)
  for (int idx = t; idx < 2500; idx += 1024) {
    int f = idx / 25, sq = (idx % 25) * 4;
    int f1 = f / 10, f2 = f - f1 * 10;
    f4v acc; acc[0]=0.f; acc[1]=0.f; acc[2]=0.f; acc[3]=0.f;
    #pragma unroll
    for (int du = 0; du < 3; ++du) {
      int nf1 = f1 + du - 1;
      if ((unsigned)nf1 >= 10u) continue;
      #pragma unroll
      for (int dv = 0; dv < 3; ++dv) {
        int nf2 = f2 + dv - 1;
        if ((unsigned)nf2 >= 10u) continue;
        float w = prm[208 + du * 3 + dv];
        f4v xv = *(const f4v*)(CORR + (nf1 * 10 + nf2) * 100 + sq);
        #pragma unroll
        for (int e = 0; e < 4; ++e) acc[e] += w * xv[e];
      }
    }
    #pragma unroll
    for (int e = 0; e < 4; ++e) { float v = S2 * acc[e] + B2; acc[e] = v > 0.f ? v : 0.f; }
    *(f4v*)(T1 + f * 100 + sq) = acc;
  }
  __syncthreads();

  // c1 second conv (3x3 over s) + bn1 -> T2 fp16
  for (int idx = t; idx < 10000; idx += 1024) {
    int f = idx / 100, s = idx - f * 100;
    int s1 = s / 10, s2 = s - s1 * 10;
    float a = 0.f;
    #pragma unroll
    for (int dh = 0; dh < 3; ++dh) {
      int ns1 = s1 + dh - 1;
      if ((unsigned)ns1 >= 10u) continue;
      #pragma unroll
      for (int dw = 0; dw < 3; ++dw) {
        int ns2 = s2 + dw - 1;
        if ((unsigned)ns2 >= 10u) continue;
        a += prm[217 + dh * 3 + dw] * T1[f * 100 + ns1 * 10 + ns2];
      }
    }
    T2h[idx] = (_Float16)(S1 * a + B1);
  }
  __syncthreads();

  // Phase C: 5 s-chunks. Window rows s1w=0..3 <-> global s1 = 2sc-1+s1w.
  const float Cf = prm[230];
  float* resb = ws + (br ? OFF_RB : OFF_RA) + it * 10000;

  for (int sc = 0; sc < 5; ++sc) {
    // conv2 16->16 GEMM (K = 9 taps x 16 i), B-frag generated from T2.
    for (int tl = wv; tl < 250; tl += 16) {
      const int p = tl * 16 + n0;               // 0..3999
      const int f = p / 40, sl = p - f * 40;
      const int s1w = sl / 10, s2 = sl - s1w * 10;
      int gs1 = 2 * sc - 1 + s1w;
      gs1 = gs1 < 0 ? 0 : (gs1 > 9 ? 9 : gs1);  // junk rows masked in conv1
      const int sg = gs1 * 10 + s2;
      const int f1 = f / 10, f2 = f - f1 * 10;
      f32x4 acc; acc[0]=0.f; acc[1]=0.f; acc[2]=0.f; acc[3]=0.f;
      #pragma unroll
      for (int c = 0; c < 5; ++c) {
        const int tE = 2 * c, tO = 2 * c + 1;
        const int dE1 = tE / 3 - 1, dE2 = tE % 3 - 1;
        const int dO1 = (tO < 9) ? tO / 3 - 1 : 0;
        const int dO2 = (tO < 9) ? tO % 3 - 1 : 0;
        const int d1 = qh ? dO1 : dE1;
        const int d2 = qh ? dO2 : dE2;
        const int nf1 = f1 + d1, nf2 = f2 + d2;
        const bool valid = ((unsigned)nf1 < 10u) && ((unsigned)nf2 < 10u);
        const int nf1c = nf1 < 0 ? 0 : (nf1 > 9 ? 9 : nf1);
        const int nf2c = nf2 < 0 ? 0 : (nf2 > 9 ? 9 : nf2);
        const float t2 = (float)T2h[(nf1c * 10 + nf2c) * 100 + sg];
        unsigned int bw[4];
        #pragma unroll
        for (int jj = 0; jj < 4; ++jj) {
          float ya = avj[2 * jj] * t2 + bpj[2 * jj];
          ya = ya > 0.f ? ya : 0.f;
          float yb = avj[2 * jj + 1] * t2 + bpj[2 * jj + 1];
          yb = yb > 0.f ? yb : 0.f;
          unsigned int pk = pack2h(ya, yb);
          bw[jj] = valid ? pk : 0u;
        }
        union { unsigned int u[4]; half8v v; } bb;
        bb.u[0] = bw[0]; bb.u[1] = bw[1]; bb.u[2] = bw[2]; bb.u[3] = bw[3];
        acc = __builtin_amdgcn_mfma_f32_16x16x32_f16(A2[c], bb.v, acc, 0, 0, 0);
      }
      // epilogue: bn2 + relu -> Y2w[p][o], o = qd*4+r
      float v0 = sc2[0] * acc[0] + bc2[0]; v0 = v0 > 0.f ? v0 : 0.f;
      float v1 = sc2[1] * acc[1] + bc2[1]; v1 = v1 > 0.f ? v1 : 0.f;
      float v2 = sc2[2] * acc[2] + bc2[2]; v2 = v2 > 0.f ? v2 : 0.f;
      float v3 = sc2[3] * acc[3] + bc2[3]; v3 = v3 > 0.f ? v3 : 0.f;
      unsigned int* dst = (unsigned int*)Y2w + p * 8 + qd * 2;
      dst[0] = pack2h(v0, v1);
      dst[1] = pack2h(v2, v3);
    }
    __syncthreads();

    // conv1-eff 16->1 GEMM over s-taps; output rows s1 = 2sc + s1w
    for (int tl = wv; tl < 125; tl += 16) {
      const int op = tl * 16 + n0;              // 0..1999
      const int f = op / 20, r2 = op - f * 20;
      const int s1w = r2 / 10, s2 = r2 - s1w * 10;
      f32x4 acc; acc[0]=0.f; acc[1]=0.f; acc[2]=0.f; acc[3]=0.f;
      #pragma unroll
      for (int c = 0; c < 5; ++c) {
        const int tE = 2 * c, tO = 2 * c + 1;
        const int hE = tE / 3, wE = tE % 3;
        const int hO = (tO < 9) ? tO / 3 : 0;
        const int wO = (tO < 9) ? tO % 3 : 0;
        const int dh = qh ? hO : hE;
        const int dw = qh ? wO : wE;
        int nsl = (s1w + dh) * 10 + s2 + dw - 1;
        const bool valid = ((unsigned)(2 * sc + s1w + dh - 1) < 10u) &&
                           ((unsigned)(s2 + dw - 1) < 10u);
        nsl = nsl < 0 ? 0 : (nsl > 39 ? 39 : nsl);
        union { half8v v; unsigned int u[4]; } bb;
        bb.v = *(const half8v*)(Y2w + (f * 40 + nsl) * 16 + i0);
        if (!valid) { bb.u[0] = 0u; bb.u[1] = 0u; bb.u[2] = 0u; bb.u[3] = 0u; }
        acc = __builtin_amdgcn_mfma_f32_16x16x32_f16(A1[c], bb.v, acc, 0, 0, 0);
      }
      if (qd == 0) {
        const int s = (2 * sc + s1w) * 10 + s2;
        const int pos = br ? (s * 100 + f) : (f * 100 + s);
        resb[pos] = acc[0] + Cf;
      }
    }
    __syncthreads();
  }
}

// ---------------------------------------------------------------------------
// per-item gaussian_normalize + softmax(/5) over each axis; attn sums
__global__ __launch_bounds__(128) void k_stats(float* __restrict__ ws)
{
  __shared__ float F[10000];
  __shared__ float mc[100], ic[100], rc[100];
  __shared__ float mr[100], ir[100], rr[100];
  const int it = blockIdx.x, t = threadIdx.x;
  const float* ra = ws + OFF_RA + it * 10000;
  const float* rb = ws + OFF_RB + it * 10000;
  for (int idx = t; idx < 10000; idx += 128) F[idx] = ra[idx] + rb[idx];
  __syncthreads();
  if (t < 100) {
    float s = 0.f;
    for (int ij = 0; ij < 100; ++ij) s += F[ij * 100 + t];
    float m = s * 0.01f;
    float ss = 0.f;
    for (int ij = 0; ij < 100; ++ij) { float d = F[ij * 100 + t] - m; ss += d * d; }
    float inv = 1.f / (sqrtf(ss * (1.f / 99.f) + 1e-5f) * 5.f);
    float den = 0.f;
    for (int ij = 0; ij < 100; ++ij) den += __expf((F[ij * 100 + t] - m) * inv);
    mc[t] = m; ic[t] = inv; rc[t] = 1.f / den;
    s = 0.f;
    for (int kl = 0; kl < 100; ++kl) s += F[t * 100 + kl];
    m = s * 0.01f;
    ss = 0.f;
    for (int kl = 0; kl < 100; ++kl) { float d = F[t * 100 + kl] - m; ss += d * d; }
    inv = 1.f / (sqrtf(ss * (1.f / 99.f) + 1e-5f) * 5.f);
    den = 0.f;
    for (int kl = 0; kl < 100; ++kl) den += __expf((F[t * 100 + kl] - m) * inv);
    mr[t] = m; ir[t] = inv; rr[t] = 1.f / den;
  }
  __syncthreads();
  if (t < 100) {
    float s = 0.f;
    for (int kl = 0; kl < 100; ++kl)
      s += __expf((F[t * 100 + kl] - mc[kl]) * ic[kl]) * rc[kl];
    ws[OFF_AS + it * 100 + t] = s;
    float s2 = 0.f;
    for (int ij = 0; ij < 100; ++ij)
      s2 += __expf((F[ij * 100 + t] - mr[ij]) * ir[ij]) * rr[ij];
    ws[OFF_AQ + it * 100 + t] = s2;
  }
}

// ---------------------------------------------------------------------------
// attention pooling + cosine similarity
__global__ __launch_bounds__(256) void k_sim(float* __restrict__ ws, float* __restrict__ out)
{
  __shared__ float asL[100], aqL[100];
  __shared__ float red[12];
  const int it = blockIdx.x, t = threadIdx.x;
  const int q = it / 5, n = it % 5;
  if (t < 100) { asL[t] = ws[OFF_AS + it * 100 + t]; aqL[t] = ws[OFF_AQ + it * 100 + t]; }
  __syncthreads();
  const float* sc = ws + OFF_SC + n * 64000;
  const float* qc = ws + OFF_QC + q * 64000;
  float dot = 0.f, na = 0.f, nb = 0.f;
  for (int c = t; c < 640; c += 256) {
    float sa = 0.f, qa = 0.f;
    for (int p = 0; p < 100; ++p) {
      sa += asL[p] * sc[c * 100 + p];
      qa += aqL[p] * qc[c * 100 + p];
    }
    sa *= 0.01f; qa *= 0.01f;
    dot += sa * qa; na += sa * sa; nb += qa * qa;
  }
  #pragma unroll
  for (int off = 32; off > 0; off >>= 1) {
    dot += __shfl_down(dot, off);
    na  += __shfl_down(na, off);
    nb  += __shfl_down(nb, off);
  }
  const int wid = t >> 6, lanei = t & 63;
  if (lanei == 0) { red[wid * 3 + 0] = dot; red[wid * 3 + 1] = na; red[wid * 3 + 2] = nb; }
  __syncthreads();
  if (t == 0) {
    dot = red[0] + red[3] + red[6] + red[9];
    na  = red[1] + red[4] + red[7] + red[10];
    nb  = red[2] + red[5] + red[8] + red[11];
    float ns = sqrtf(na); ns = ns > 1e-8f ? ns : 1e-8f;
    float nq2 = sqrtf(nb); nq2 = nq2 > 1e-8f ? nq2 : 1e-8f;
    out[it] = dot / (ns * nq2) * 5.f;
  }
}

// ---------------------------------------------------------------------------
extern "C" void kernel_launch(void* const* d_in, const int* in_sizes, int n_in,
                              void* d_out, int out_size, void* d_ws, size_t ws_size,
                              hipStream_t stream)
{
  (void)in_sizes; (void)n_in; (void)out_size; (void)ws_size;
  const float* spt    = (const float*)d_in[0];
  const float* qry    = (const float*)d_in[1];
  const float* w1x1   = (const float*)d_in[2];
  const float* bn1x1  = (const float*)d_in[3];
  const float* c1c2w  = (const float*)d_in[4];
  const float* c1bn2  = (const float*)d_in[5];
  const float* c1c1w  = (const float*)d_in[6];
  const float* c1bn1  = (const float*)d_in[7];
  const float* c1pj   = (const float*)d_in[8];
  const float* c1bnp  = (const float*)d_in[9];
  const float* c2c2w  = (const float*)d_in[10];
  const float* c2bn2  = (const float*)d_in[11];
  const float* c2c1w  = (const float*)d_in[12];
  const float* c2bn1  = (const float*)d_in[13];
  const float* c2pj   = (const float*)d_in[14];
  const float* c2bnp  = (const float*)d_in[15];
  float* ws  = (float*)d_ws;
  float* out = (float*)d_out;

  k_prep<<<1, 256, 0, stream>>>(c1c2w, c1bn2, c1c1w, c1bn1, c1pj, c1bnp,
                                c2c2w, c2bn2, c2c1w, c2bn1, c2pj, c2bnp,
                                ws + OFF_PRM);
  k_center<<<80, 256, 0, stream>>>(spt, qry, ws, out);
  k_feat<<<80, 512, 0, stream>>>(w1x1, bn1x1, ws);

  // 148000 B dynamic LDS (>64KB default cap) — opt in each call (idempotent)
  (void)hipFuncSetAttribute((const void*)k_cca,
                            hipFuncAttributeMaxDynamicSharedMemorySize, 148000);
  k_cca<<<NITEM * 2, 1024, 148000, stream>>>(ws);

  k_stats<<<NITEM, 128, 0, stream>>>(ws);
  k_sim<<<NITEM, 256, 0, stream>>>(ws, out);
}

// Round 5
// 517.983 us; speedup vs baseline: 5.7276x; 1.7713x over previous
//
#include <hip/hip_runtime.h>

// ---------------------------------------------------------------------------
// CCALayer: spt (1,5,640,10,10)  qry (75,640,10,10)
// Q=75, way=5, C=640, Cf=64, P=100 (10x10), items=375
// Output: sim (75,5) [375] ++ qry_pooled (75,640) [48000]
// ---------------------------------------------------------------------------

#define NITEM 375

// ws layout (float offsets)
#define OFF_SC  0            // centered support   5*640*100
#define OFF_QC  320000       // centered query    75*640*100
#define OFF_SF  5120000      // sf  5*64*100
#define OFF_QF  5152000      // qf 75*64*100
#define OFF_RA  5632000      // branch-A result 375*10000
#define OFF_RB  9382000      // branch-B result 375*10000
#define OFF_AS  13132000     // attn_s 375*100
#define OFF_AQ  13169500     // attn_q 375*100
#define OFF_PRM 13207000     // folded params

// prm layout (floats):
// [0..143] W1eff[ds][i]; [144..159] Av; [160..175] Bp
// [176..191] S2c2; [192..207] B2c2
// [208..216] w2c1; [217..225] w1c1
// [226] S2 [227] B2 [228] S1 [229] B1 [230] Cf
// PK2 (conv2 A-frags, 2560 fp16) at floats [232,1512)
// PK1 (conv1eff A-frags, 2560 fp16) at floats [1512,2792)
#define PK2F 232
#define PK1F 1512

// k_cca LDS byte map (dynamic, 148768 total):
//  phase corr : T2h[0,20000) | sfL[20480,46080) qfL[46080,71680) CORR[71680,111680)
//  phase c1   : T1[20480,60480) (c1a: CORR->T1; c1b: T1->T2h)
//  phase conv : Y1 slabs 3x32000 at 20480 (+sl*32000; halves +0/+16000)
//               ZP (16B zeros) at 116480 ; Y2 at 116512 (halves +0/+16128)
#define Y1S   20480
#define Y1HALF 16000
#define ZPB   116480
#define Y2S   116512
#define Y2HALF 16128
#define LDS_TOTAL 148768

typedef float f4v __attribute__((ext_vector_type(4)));
typedef float f32x4 __attribute__((ext_vector_type(4)));
typedef _Float16 half8v __attribute__((ext_vector_type(8)));
typedef __fp16 fp16x2 __attribute__((ext_vector_type(2)));
typedef unsigned int u32x4 __attribute__((ext_vector_type(4)));
typedef unsigned int u32x2 __attribute__((ext_vector_type(2)));

__device__ __forceinline__ unsigned int pkrtz(float a, float b) {
  union { fp16x2 h; unsigned int u; } cv;
  cv.h = __builtin_amdgcn_cvt_pkrtz(a, b);
  return cv.u;
}

// ---------------------------------------------------------------------------
__global__ __launch_bounds__(256) void k_prep(
    const float* __restrict__ c1c2w, const float* __restrict__ c1bn2,
    const float* __restrict__ c1c1w, const float* __restrict__ c1bn1,
    const float* __restrict__ c1pj,  const float* __restrict__ c1bnp,
    const float* __restrict__ c2c2w, const float* __restrict__ c2bn2,
    const float* __restrict__ c2c1w, const float* __restrict__ c2bn1,
    const float* __restrict__ c2pj,  const float* __restrict__ c2bnp,
    float* __restrict__ prm)
{
  const int t = threadIdx.x;
  const float eps = 1e-5f;

  // W1eff[ds][i]: c2 conv1 + bn1 + proj + bnp folded 16->1
  for (int idx = t; idx < 144; idx += 256) {
    int ds = idx / 16, i = idx % 16;
    float spv = c2bnp[0] / sqrtf(c2bnp[3] + eps);
    float acc = 0.f;
    for (int o = 0; o < 16; ++o) {
      float s1 = c2bn1[o] / sqrtf(c2bn1[48 + o] + eps);
      acc += c2pj[o] * s1 * c2c1w[(o * 16 + i) * 9 + ds];
    }
    prm[idx] = spv * acc;
  }
  for (int i = t; i < 16; i += 256) {
    float s = c1bnp[i] / sqrtf(c1bnp[48 + i] + eps);
    prm[144 + i] = s * c1pj[i];
    prm[160 + i] = c1bnp[16 + i] - c1bnp[32 + i] * s;
  }
  for (int o = t; o < 16; o += 256) {
    float s = c2bn2[o] / sqrtf(c2bn2[48 + o] + eps);
    prm[176 + o] = s;
    prm[192 + o] = c2bn2[16 + o] - c2bn2[32 + o] * s;
  }
  for (int k = t; k < 9; k += 256) {
    prm[208 + k] = c1c2w[k];
    prm[217 + k] = c1c1w[k];
  }
  if (t == 0) {
    float S2 = c1bn2[0] / sqrtf(c1bn2[3] + eps);
    prm[226] = S2;
    prm[227] = c1bn2[1] - c1bn2[2] * S2;
    float S1 = c1bn1[0] / sqrtf(c1bn1[3] + eps);
    prm[228] = S1;
    prm[229] = c1bn1[1] - c1bn1[2] * S1;
    float spv = c2bnp[0] / sqrtf(c2bnp[3] + eps);
    float k0 = 0.f;
    for (int o = 0; o < 16; ++o) {
      float s1 = c2bn1[o] / sqrtf(c2bn1[48 + o] + eps);
      k0 += c2pj[o] * (c2bn1[16 + o] - c2bn1[32 + o] * s1);
    }
    prm[230] = spv * (k0 - c2bnp[2]) + c2bnp[1];
    prm[231] = 0.f;
  }
  __syncthreads();

  // PK2: conv2 A-fragments. A[m=o=lane&15][k=quad*8+j], tap=2c+(quad>>1),
  // i=(quad&1)*8+j. tap 9 = zero pad.
  _Float16* pk2 = (_Float16*)(prm + PK2F);
  for (int idx = t; idx < 2560; idx += 256) {
    int c = idx >> 9, rem = idx & 511;
    int ln = rem >> 3, j = rem & 7;
    int o = ln & 15, qq = ln >> 4;
    int tap = 2 * c + (qq >> 1);
    int i = (qq & 1) * 8 + j;
    float v = (tap < 9) ? c2c2w[(o * 16 + i) * 9 + tap] : 0.f;
    pk2[idx] = (_Float16)v;
  }
  // PK1: conv1-eff A-fragments (row m=0 only = W1eff, rest 0)
  _Float16* pk1 = (_Float16*)(prm + PK1F);
  for (int idx = t; idx < 2560; idx += 256) {
    int c = idx >> 9, rem = idx & 511;
    int ln = rem >> 3, j = rem & 7;
    int m = ln & 15, qq = ln >> 4;
    int k = c * 32 + qq * 8 + j;
    int tp = k >> 4, i = k & 15;
    float v = (m == 0 && tp < 9) ? prm[tp * 16 + i] : 0.f;
    pk1[idx] = (_Float16)v;
  }
}

// ---------------------------------------------------------------------------
// center features + qry_pooled
__global__ __launch_bounds__(256) void k_center(
    const float* __restrict__ spt, const float* __restrict__ qry,
    float* __restrict__ ws, float* __restrict__ out)
{
  const int b = blockIdx.x, t = threadIdx.x;
  const float* src = (b < 5) ? spt + b * 64000 : qry + (b - 5) * 64000;
  float* dst = (b < 5) ? ws + OFF_SC + b * 64000 : ws + OFF_QC + (b - 5) * 64000;
  __shared__ float mpp[2][100];
  __shared__ __align__(16) float mp[100];
  __shared__ float msum;
  if (t < 200) {
    int hh = t / 100, p = t - hh * 100;
    float s = 0.f;
    for (int c = hh; c < 640; c += 2) s += src[c * 100 + p];
    mpp[hh][p] = s;
  }
  __syncthreads();
  if (t < 100) mp[t] = (mpp[0][t] + mpp[1][t]) * (1.f / 640.f);
  __syncthreads();
  if (t == 0) { float s = 0.f; for (int p = 0; p < 100; ++p) s += mp[p]; msum = s; }
  const f4v* s4 = (const f4v*)src;
  f4v* d4 = (f4v*)dst;
  for (int idx = t; idx < 16000; idx += 256) {
    const f4v m4 = *(const f4v*)(mp + (idx % 25) * 4);
    f4v x = s4[idx];
    #pragma unroll
    for (int e = 0; e < 4; ++e) x[e] = x[e] - m4[e];
    d4[idx] = x;
  }
  __syncthreads();
  if (b >= 5) {
    for (int c = t; c < 640; c += 256) {
      float s = 0.f;
      for (int p = 0; p < 100; ++p) s += src[c * 100 + p];
      out[375 + (b - 5) * 640 + c] = (s - msum) * 0.01f;
    }
  }
}

// ---------------------------------------------------------------------------
// 1x1 conv 640->64 + BN + relu + per-position L2 normalize
__global__ __launch_bounds__(512) void k_feat(
    const float* __restrict__ w1x1, const float* __restrict__ bn1x1,
    float* __restrict__ ws)
{
  const int b = blockIdx.x, t = threadIdx.x;
  const float* src = (b < 5) ? ws + OFF_SC + b * 64000 : ws + OFF_QC + (b - 5) * 64000;
  float* dst = (b < 5) ? ws + OFF_SF + b * 6400 : ws + OFF_QF + (b - 5) * 6400;

  __shared__ float xch[6400];
  __shared__ float wch[4096];
  __shared__ float rn[100];

  float acc[16];
  #pragma unroll
  for (int k = 0; k < 16; ++k) acc[k] = 0.f;

  const int ot = t / 25, pt = t % 25;
  const int o0 = ot * 4, p0 = pt * 4;

  for (int cc = 0; cc < 10; ++cc) {
    __syncthreads();
    for (int idx = t; idx < 6400; idx += 512) xch[idx] = src[cc * 6400 + idx];
    for (int idx = t; idx < 4096; idx += 512) {
      int o = idx >> 6, c = idx & 63;
      wch[idx] = w1x1[o * 640 + cc * 64 + c];
    }
    __syncthreads();
    if (t < 400) {
      for (int c = 0; c < 64; ++c) {
        float xv[4], wv[4];
        #pragma unroll
        for (int k = 0; k < 4; ++k) xv[k] = xch[c * 100 + p0 + k];
        #pragma unroll
        for (int j = 0; j < 4; ++j) wv[j] = wch[(o0 + j) * 64 + c];
        #pragma unroll
        for (int j = 0; j < 4; ++j)
          #pragma unroll
          for (int k = 0; k < 4; ++k) acc[j * 4 + k] += wv[j] * xv[k];
      }
    }
  }
  __syncthreads();
  float* fL = xch;
  if (t < 400) {
    #pragma unroll
    for (int j = 0; j < 4; ++j) {
      int o = o0 + j;
      float scv = bn1x1[o] / sqrtf(bn1x1[192 + o] + 1e-5f);
      float shv = bn1x1[64 + o] - bn1x1[128 + o] * scv;
      #pragma unroll
      for (int k = 0; k < 4; ++k) {
        float v = scv * acc[j * 4 + k] + shv;
        fL[o * 100 + p0 + k] = v > 0.f ? v : 0.f;
      }
    }
  }
  __syncthreads();
  if (t < 100) {
    float s = 0.f;
    for (int o = 0; o < 64; ++o) { float v = fL[o * 100 + t]; s += v * v; }
    float nr = sqrtf(s);
    rn[t] = 1.f / (nr > 1e-8f ? nr : 1e-8f);
  }
  __syncthreads();
  for (int idx = t; idx < 6400; idx += 512) dst[idx] = fL[idx] * rn[idx % 100];
}

// ---------------------------------------------------------------------------
// Fused corr + cca branch. grid = 375 items x 2 branches.
// c2 stage: Y1 materialized in LDS (3 rotating f1-row slabs), conv2 + conv1
// MFMAs read b128 B-fragments directly; tap offsets folded into per-lane base
// pointers; boundary taps redirected to a 16-B zero page.
__global__ __launch_bounds__(1024) __attribute__((amdgpu_waves_per_eu(4, 4)))
void k_cca(float* __restrict__ ws)
{
  extern __shared__ char smem[];
  _Float16* T2h = (_Float16*)smem;
  float* sfL  = (float*)(smem + 20480);
  float* qfL  = (float*)(smem + 46080);
  float* CORR = (float*)(smem + 71680);
  float* T1   = (float*)(smem + 20480);

  const float* prm = ws + OFF_PRM;
  const int bid = blockIdx.x;
  const int it = bid >> 1, br = bid & 1;
  const int q = it / 5, n = it % 5;
  const int t = threadIdx.x;
  const int lane = t & 63, wv = t >> 6;
  const int n0 = lane & 15, qd = (lane >> 4) & 3;
  const int qh = qd >> 1, ih = qd & 1;

  // MFMA A-fragments (weights) resident in registers
  const _Float16* pk2 = (const _Float16*)(prm + PK2F);
  const _Float16* pk1 = (const _Float16*)(prm + PK1F);
  half8v A2[5], A1[5];
  #pragma unroll
  for (int c = 0; c < 5; ++c) {
    A2[c] = *(const half8v*)(pk2 + c * 512 + lane * 8);
    A1[c] = *(const half8v*)(pk1 + c * 512 + lane * 8);
  }
  float sc2[4], bc2[4];
  #pragma unroll
  for (int r = 0; r < 4; ++r) { sc2[r] = prm[176 + qd * 4 + r]; bc2[r] = prm[192 + qd * 4 + r]; }

  // tap tables: tap tp -> (d1,d2) = (tp/3-1, tp%3-1); even taps (qh=0) / odd (qh=1)
  const int d1E[5] = {-1,-1, 0, 0, 1}, d2E[5] = {-1, 1, 0,-1, 1};
  const int d1O[5] = {-1, 0, 0, 1, 0}, d2O[5] = { 0,-1, 1, 0, 0};

  // conv1 point offsets (d1*10+d2)*16 bytes, per-lane by qh
  int D1[5];
  #pragma unroll
  for (int c = 0; c < 5; ++c)
    D1[c] = (qh ? (d1O[c] * 10 + d2O[c]) : (d1E[c] * 10 + d2E[c])) * 16;
  const int BY = Y2S + ih * Y2HALF;   // conv1 B-read half base
  const int ihY1 = ih * Y1HALF;

  // ---- stage sf/qf ----
  {
    const f4v* sf4 = (const f4v*)(ws + OFF_SF + n * 6400);
    const f4v* qf4 = (const f4v*)(ws + OFF_QF + q * 6400);
    f4v* sL4 = (f4v*)sfL; f4v* qL4 = (f4v*)qfL;
    for (int idx = t; idx < 1600; idx += 1024) { sL4[idx] = sf4[idx]; qL4[idx] = qf4[idx]; }
  }
  __syncthreads();

  // ---- corr (4x4 register tile). Generic layout CORR[f*100+s] ----
  if (t < 625) {
    const int ij0 = (t / 25) * 4, kl0 = (t % 25) * 4;
    f4v acc4[4];
    #pragma unroll
    for (int jj = 0; jj < 4; ++jj) { acc4[jj][0]=0.f; acc4[jj][1]=0.f; acc4[jj][2]=0.f; acc4[jj][3]=0.f; }
    for (int c = 0; c < 64; ++c) {
      f4v sv = *(const f4v*)(sfL + c * 100 + ij0);
      f4v qv = *(const f4v*)(qfL + c * 100 + kl0);
      #pragma unroll
      for (int jj = 0; jj < 4; ++jj)
        #pragma unroll
        for (int e = 0; e < 4; ++e) acc4[jj][e] += sv[jj] * qv[e];
    }
    if (br == 0) {
      #pragma unroll
      for (int jj = 0; jj < 4; ++jj) *(f4v*)(CORR + (ij0 + jj) * 100 + kl0) = acc4[jj];
    } else {
      #pragma unroll
      for (int kk = 0; kk < 4; ++kk) {
        f4v tr;
        #pragma unroll
        for (int jj = 0; jj < 4; ++jj) tr[jj] = acc4[jj][kk];
        *(f4v*)(CORR + (kl0 + kk) * 100 + ij0) = tr;
      }
    }
  }
  __syncthreads();

  const float S2 = prm[226], B2 = prm[227], S1 = prm[228], B1 = prm[229];

  // ---- c1a: 3x3 conv over f + bn2 + relu -> T1 ----
  for (int idx = t; idx < 2500; idx += 1024) {
    int f = idx / 25, sq = (idx % 25) * 4;
    int f1 = f / 10, f2 = f - f1 * 10;
    f4v acc; acc[0]=0.f; acc[1]=0.f; acc[2]=0.f; acc[3]=0.f;
    #pragma unroll
    for (int du = 0; du < 3; ++du) {
      int nf1 = f1 + du - 1;
      if ((unsigned)nf1 >= 10u) continue;
      #pragma unroll
      for (int dv = 0; dv < 3; ++dv) {
        int nf2 = f2 + dv - 1;
        if ((unsigned)nf2 >= 10u) continue;
        float w = prm[208 + du * 3 + dv];
        f4v xv = *(const f4v*)(CORR + (nf1 * 10 + nf2) * 100 + sq);
        #pragma unroll
        for (int e = 0; e < 4; ++e) acc[e] += w * xv[e];
      }
    }
    #pragma unroll
    for (int e = 0; e < 4; ++e) { float v = S2 * acc[e] + B2; acc[e] = v > 0.f ? v : 0.f; }
    *(f4v*)(T1 + f * 100 + sq) = acc;
  }
  __syncthreads();

  // ---- c1b: 3x3 conv over s + bn1 -> T2h (vectorized, one (f,s1) row/thread) --
  if (t < 1000) {
    const int f = t / 10, s1 = t - (t / 10) * 10;
    const float* rowB = T1 + f * 100;
    f4v r[3][3];
    float w[3][3];
    #pragma unroll
    for (int dh = 0; dh < 3; ++dh) {
      int rr = s1 + dh - 1;
      bool okr = (unsigned)rr < 10u;
      int rc = rr < 0 ? 0 : (rr > 9 ? 9 : rr);
      const float* rp = rowB + rc * 10;
      r[dh][0] = *(const f4v*)(rp);
      r[dh][1] = *(const f4v*)(rp + 4);
      r[dh][2] = *(const f4v*)(rp + 8);   // cols 10,11 junk - never used
      #pragma unroll
      for (int dw = 0; dw < 3; ++dw) w[dh][dw] = okr ? prm[217 + dh * 3 + dw] : 0.f;
    }
    float o[10];
    #pragma unroll
    for (int s2 = 0; s2 < 10; ++s2) {
      float a = 0.f;
      #pragma unroll
      for (int dh = 0; dh < 3; ++dh)
        #pragma unroll
        for (int dw = 0; dw < 3; ++dw) {
          int col = s2 + dw - 1;
          if (col < 0 || col > 9) continue;   // static boundary exclusion
          a += w[dh][dw] * r[dh][col >> 2][col & 3];
        }
      o[s2] = a;
    }
    unsigned int* dst = (unsigned int*)((char*)T2h + (f * 100 + s1 * 10) * 2);
    #pragma unroll
    for (int k = 0; k < 5; ++k)
      dst[k] = pkrtz(S1 * o[2 * k] + B1, S1 * o[2 * k + 1] + B1);
  }
  __syncthreads();

  // ---- phase C prologue: gen Y1 slabs for f1=0,1; zero the zero-page ----
  #define GEN_Y1(F1N)                                                          \
    if (t < 1000) {                                                            \
      const int _sl = (F1N) % 3;                                               \
      const float t2 = (float)T2h[(F1N) * 1000 + t];                           \
      unsigned int d[8];                                                       \
      _Pragma("unroll")                                                        \
      for (int j = 0; j < 8; ++j) {                                            \
        float ya = fmaxf(prm[144 + 2 * j] * t2 + prm[160 + 2 * j], 0.f);       \
        float yb = fmaxf(prm[145 + 2 * j] * t2 + prm[161 + 2 * j], 0.f);       \
        d[j] = pkrtz(ya, yb);                                                  \
      }                                                                        \
      u32x4 lo, hi;                                                            \
      lo[0]=d[0]; lo[1]=d[1]; lo[2]=d[2]; lo[3]=d[3];                          \
      hi[0]=d[4]; hi[1]=d[5]; hi[2]=d[6]; hi[3]=d[7];                          \
      *(u32x4*)(smem + Y1S + _sl * 32000 + t * 16) = lo;                       \
      *(u32x4*)(smem + Y1S + _sl * 32000 + Y1HALF + t * 16) = hi;              \
    }

  GEN_Y1(0)
  GEN_Y1(1)
  if (t >= 1000 && t < 1004) *(unsigned int*)(smem + ZPB + (t - 1000) * 4) = 0u;
  __syncthreads();

  const float Cf = prm[230];
  float* resb = ws + (br ? OFF_RB : OFF_RA) + it * 10000;

  // ---- g-loop over output f1-rows ----
  for (int g = 0; g < 10; ++g) {
    // per-g per-lane conv2 base pointers + f1-validity
    const int sl0 = g % 3, slP = (g + 1) % 3, slM = (g + 2) % 3; // (g-1)%3
    const int baseM = Y1S + slM * 32000;
    const int base0 = Y1S + sl0 * 32000;
    const int baseP = Y1S + slP * 32000;
    const bool okM = (g >= 1), okP = (g <= 8);
    int Bc[5]; bool v1c[5];
    #pragma unroll
    for (int c = 0; c < 5; ++c) {
      int bE = (d1E[c] < 0 ? baseM : (d1E[c] > 0 ? baseP : base0)) + d2E[c] * 1600;
      int bO = (d1O[c] < 0 ? baseM : (d1O[c] > 0 ? baseP : base0)) + d2O[c] * 1600;
      Bc[c] = (qh ? bO : bE) + ihY1;
      bool vE = d1E[c] < 0 ? okM : (d1E[c] > 0 ? okP : true);
      bool vO = (c == 4) ? false : (d1O[c] < 0 ? okM : (d1O[c] > 0 ? okP : true));
      v1c[c] = qh ? vO : vE;
    }

    // conv2: 16->16 3x3 over f, MFMA, B from Y1 LDS
    for (int tile = wv; tile < 63; tile += 16) {
      const int p = tile * 16 + n0;
      const int pcp = p < 1000 ? p : 999;
      const int pp = pcp * 16;
      const int f2 = pcp / 100;
      const bool fm = f2 > 0, fp = f2 < 9;
      f32x4 acc; acc[0]=0.f; acc[1]=0.f; acc[2]=0.f; acc[3]=0.f;
      #pragma unroll
      for (int c = 0; c < 5; ++c) {
        bool v2E = d2E[c] < 0 ? fm : (d2E[c] > 0 ? fp : true);
        bool v2O = d2O[c] < 0 ? fm : (d2O[c] > 0 ? fp : true);
        bool v = v1c[c] && (qh ? v2O : v2E);
        int addr = v ? (Bc[c] + pp) : ZPB;
        half8v b = *(const half8v*)(smem + addr);
        acc = __builtin_amdgcn_mfma_f32_16x16x32_f16(A2[c], b, acc, 0, 0, 0);
      }
      // epilogue: bn2+relu, pack fp16, write Y2 (half = qh, off = ih*8)
      float v0 = fmaxf(sc2[0] * acc[0] + bc2[0], 0.f);
      float v1 = fmaxf(sc2[1] * acc[1] + bc2[1], 0.f);
      float v2 = fmaxf(sc2[2] * acc[2] + bc2[2], 0.f);
      float v3 = fmaxf(sc2[3] * acc[3] + bc2[3], 0.f);
      u32x2 wq; wq[0] = pkrtz(v0, v1); wq[1] = pkrtz(v2, v3);
      *(u32x2*)(smem + Y2S + qh * Y2HALF + p * 16 + ih * 8) = wq;
    }
    __syncthreads();

    // conv1-eff: 16->1 3x3 over s, MFMA row0; plus gen Y1(g+2)
    for (int tile = wv; tile < 63; tile += 16) {
      const int p = tile * 16 + n0;
      const int pcp = p < 1000 ? p : 999;
      const int b0 = BY + pcp * 16;
      const int f2 = pcp / 100;
      const int s = pcp - f2 * 100;
      const int s1 = s / 10, s2 = s - s1 * 10;
      const bool rm = s1 > 0, rp = s1 < 9, cm = s2 > 0, cp = s2 < 9;
      f32x4 acc; acc[0]=0.f; acc[1]=0.f; acc[2]=0.f; acc[3]=0.f;
      #pragma unroll
      for (int c = 0; c < 5; ++c) {
        bool vE = (d1E[c] < 0 ? rm : (d1E[c] > 0 ? rp : true)) &&
                  (d2E[c] < 0 ? cm : (d2E[c] > 0 ? cp : true));
        bool vO = (c == 4) ? false :
                  ((d1O[c] < 0 ? rm : (d1O[c] > 0 ? rp : true)) &&
                   (d2O[c] < 0 ? cm : (d2O[c] > 0 ? cp : true)));
        bool v = qh ? vO : vE;
        int addr = v ? (b0 + D1[c]) : ZPB;
        half8v b = *(const half8v*)(smem + addr);
        acc = __builtin_amdgcn_mfma_f32_16x16x32_f16(A1[c], b, acc, 0, 0, 0);
      }
      if (qd == 0 && p < 1000) {
        const int fg = g * 10 + f2;
        const int pos = br ? (s * 100 + fg) : (fg * 100 + s);
        resb[pos] = acc[0] + Cf;
      }
    }
    if (g + 2 <= 9) { GEN_Y1(g + 2) }
    __syncthreads();
  }
  #undef GEN_Y1
}

// ---------------------------------------------------------------------------
// per-item gaussian_normalize + softmax(/5) over each axis; attn sums
__global__ __launch_bounds__(256) void k_stats(float* __restrict__ ws)
{
  __shared__ float F[10000];
  __shared__ float mc[100], ic[100], rc[100];
  __shared__ float mr[100], ir[100], rr[100];
  const int it = blockIdx.x, t = threadIdx.x;
  const f4v* ra4 = (const f4v*)(ws + OFF_RA + it * 10000);
  const f4v* rb4 = (const f4v*)(ws + OFF_RB + it * 10000);
  f4v* F4 = (f4v*)F;
  for (int idx = t; idx < 2500; idx += 256) {
    f4v a = ra4[idx], b = rb4[idx];
    #pragma unroll
    for (int e = 0; e < 4; ++e) a[e] += b[e];
    F4[idx] = a;
  }
  __syncthreads();
  if (t < 100) {
    // column kl=t (over ij): corr_s axis
    float s = 0.f;
    for (int ij = 0; ij < 100; ++ij) s += F[ij * 100 + t];
    float m = s * 0.01f;
    float ss = 0.f;
    for (int ij = 0; ij < 100; ++ij) { float d = F[ij * 100 + t] - m; ss += d * d; }
    float inv = 1.f / (sqrtf(ss * (1.f / 99.f) + 1e-5f) * 5.f);
    float den = 0.f;
    for (int ij = 0; ij < 100; ++ij) den += __expf((F[ij * 100 + t] - m) * inv);
    mc[t] = m; ic[t] = inv; rc[t] = 1.f / den;
  } else if (t < 200) {
    // row ij=t-100 (over kl): corr_q axis
    const int r = t - 100;
    float s = 0.f;
    for (int kl = 0; kl < 100; ++kl) s += F[r * 100 + kl];
    float m = s * 0.01f;
    float ss = 0.f;
    for (int kl = 0; kl < 100; ++kl) { float d = F[r * 100 + kl] - m; ss += d * d; }
    float inv = 1.f / (sqrtf(ss * (1.f / 99.f) + 1e-5f) * 5.f);
    float den = 0.f;
    for (int kl = 0; kl < 100; ++kl) den += __expf((F[r * 100 + kl] - m) * inv);
    mr[r] = m; ir[r] = inv; rr[r] = 1.f / den;
  }
  __syncthreads();
  if (t < 100) {
    float s = 0.f;
    for (int kl = 0; kl < 100; ++kl)
      s += __expf((F[t * 100 + kl] - mc[kl]) * ic[kl]) * rc[kl];
    ws[OFF_AS + it * 100 + t] = s;                    // attn_s[ij=t]
  } else if (t < 200) {
    const int r = t - 100;
    float s2 = 0.f;
    for (int ij = 0; ij < 100; ++ij)
      s2 += __expf((F[ij * 100 + r] - mr[ij]) * ir[ij]) * rr[ij];
    ws[OFF_AQ + it * 100 + r] = s2;                   // attn_q[kl=r]
  }
}

// ---------------------------------------------------------------------------
// attention pooling + cosine similarity
__global__ __launch_bounds__(256) void k_sim(float* __restrict__ ws, float* __restrict__ out)
{
  __shared__ float asL[100], aqL[100];
  __shared__ float red[12];
  const int it = blockIdx.x, t = threadIdx.x;
  const int q = it / 5, n = it % 5;
  if (t < 100) { asL[t] = ws[OFF_AS + it * 100 + t]; aqL[t] = ws[OFF_AQ + it * 100 + t]; }
  __syncthreads();
  const float* sc = ws + OFF_SC + n * 64000;
  const float* qc = ws + OFF_QC + q * 64000;
  float dot = 0.f, na = 0.f, nb = 0.f;
  for (int c = t; c < 640; c += 256) {
    float sa = 0.f, qa = 0.f;
    for (int p = 0; p < 100; ++p) {
      sa += asL[p] * sc[c * 100 + p];
      qa += aqL[p] * qc[c * 100 + p];
    }
    sa *= 0.01f; qa *= 0.01f;
    dot += sa * qa; na += sa * sa; nb += qa * qa;
  }
  #pragma unroll
  for (int off = 32; off > 0; off >>= 1) {
    dot += __shfl_down(dot, off);
    na  += __shfl_down(na, off);
    nb  += __shfl_down(nb, off);
  }
  const int wid = t >> 6, lanei = t & 63;
  if (lanei == 0) { red[wid * 3 + 0] = dot; red[wid * 3 + 1] = na; red[wid * 3 + 2] = nb; }
  __syncthreads();
  if (t == 0) {
    dot = red[0] + red[3] + red[6] + red[9];
    na  = red[1] + red[4] + red[7] + red[10];
    nb  = red[2] + red[5] + red[8] + red[11];
    float ns = sqrtf(na); ns = ns > 1e-8f ? ns : 1e-8f;
    float nq2 = sqrtf(nb); nq2 = nq2 > 1e-8f ? nq2 : 1e-8f;
    out[it] = dot / (ns * nq2) * 5.f;   // /TEMPERATURE(0.2)
  }
}

// ---------------------------------------------------------------------------
extern "C" void kernel_launch(void* const* d_in, const int* in_sizes, int n_in,
                              void* d_out, int out_size, void* d_ws, size_t ws_size,
                              hipStream_t stream)
{
  (void)in_sizes; (void)n_in; (void)out_size; (void)ws_size;
  const float* spt    = (const float*)d_in[0];
  const float* qry    = (const float*)d_in[1];
  const float* w1x1   = (const float*)d_in[2];
  const float* bn1x1  = (const float*)d_in[3];
  const float* c1c2w  = (const float*)d_in[4];
  const float* c1bn2  = (const float*)d_in[5];
  const float* c1c1w  = (const float*)d_in[6];
  const float* c1bn1  = (const float*)d_in[7];
  const float* c1pj   = (const float*)d_in[8];
  const float* c1bnp  = (const float*)d_in[9];
  const float* c2c2w  = (const float*)d_in[10];
  const float* c2bn2  = (const float*)d_in[11];
  const float* c2c1w  = (const float*)d_in[12];
  const float* c2bn1  = (const float*)d_in[13];
  const float* c2pj   = (const float*)d_in[14];
  const float* c2bnp  = (const float*)d_in[15];
  float* ws  = (float*)d_ws;
  float* out = (float*)d_out;

  k_prep<<<1, 256, 0, stream>>>(c1c2w, c1bn2, c1c1w, c1bn1, c1pj, c1bnp,
                                c2c2w, c2bn2, c2c1w, c2bn1, c2pj, c2bnp,
                                ws + OFF_PRM);
  k_center<<<80, 256, 0, stream>>>(spt, qry, ws, out);
  k_feat<<<80, 512, 0, stream>>>(w1x1, bn1x1, ws);

  (void)hipFuncSetAttribute((const void*)k_cca,
                            hipFuncAttributeMaxDynamicSharedMemorySize, LDS_TOTAL);
  k_cca<<<NITEM * 2, 1024, LDS_TOTAL, stream>>>(ws);

  k_stats<<<NITEM, 256, 0, stream>>>(ws);
  k_sim<<<NITEM, 256, 0, stream>>>(ws, out);
}

// Round 6
// 415.192 us; speedup vs baseline: 7.1456x; 1.2476x over previous
//
#include <hip/hip_runtime.h>

// ---------------------------------------------------------------------------
// CCALayer: spt (1,5,640,10,10)  qry (75,640,10,10)
// Q=75, way=5, C=640, Cf=64, P=100 (10x10), items=375
// Output: sim (75,5) [375] ++ qry_pooled (75,640) [48000]
// ---------------------------------------------------------------------------

#define NITEM 375

// ws layout (float offsets)
#define OFF_XTS 0            // raw support transposed fp16 [5][100 p][640 c]   (32000 fl/b)
#define OFF_XTQ 160000       // raw query transposed fp16 [75][100][640]
#define OFF_MP  2560000      // per-image position means [80][100] f32
#define OFF_SF  2568000      // sf  5*64*100 f32 [c][p]
#define OFF_QF  2600000      // qf 75*64*100
#define OFF_RA  3080000      // branch-A result 375*10000
#define OFF_RB  6830000      // branch-B result 375*10000
#define OFF_AS  10580000     // attn_s 375*100
#define OFF_AQ  10617500     // attn_q 375*100
#define OFF_PRM 10655000     // folded params

// prm layout (floats):
// [0..143] W1eff[ds][i]; [144..159] Av; [160..175] Bp
// [176..191] S2c2; [192..207] B2c2
// [208..216] w2c1; [217..225] w1c1
// [226] S2 [227] B2 [228] S1 [229] B1 [230] Cf
// PK2 (conv2 A-frags, 2560 fp16) at floats [232,1512)
// PK1 (conv1eff A-frags, 2560 fp16) at floats [1512,2792)
// WSUM [2792,2856) ; SCV [2856,2920) ; SHV [2920,2984)
// PKW (feat GEMM A-frags, 51200 fp16) at floats [2984,28584)
#define PK2F 232
#define PK1F 1512
#define WSUMF 2792
#define SCVF 2856
#define SHVF 2920
#define PKWF 2984

// k_cca LDS byte map (dynamic, 148768 total):
//  phase corr : T2h[0,20000) | sfL[20480,46080) qfL[46080,71680) CORR[71680,111680)
//  phase c1   : T1[20480,60480) (c1a: CORR->T1; c1b: T1->T2h)
//  phase conv : Y1 slabs 3x32000 at 20480 (+sl*32000; halves +0/+16000)
//               ZP (16B zeros) at 116480 ; Y2 at 116512 (halves +0/+16128)
#define Y1S   20480
#define Y1HALF 16000
#define ZPB   116480
#define Y2S   116512
#define Y2HALF 16128
#define LDS_TOTAL 148768

typedef float f4v __attribute__((ext_vector_type(4)));
typedef float f32x4 __attribute__((ext_vector_type(4)));
typedef _Float16 half8v __attribute__((ext_vector_type(8)));
typedef __fp16 fp16x2 __attribute__((ext_vector_type(2)));
typedef unsigned int u32x4 __attribute__((ext_vector_type(4)));
typedef unsigned int u32x2 __attribute__((ext_vector_type(2)));

__device__ __forceinline__ unsigned int pkrtz(float a, float b) {
  union { fp16x2 h; unsigned int u; } cv;
  cv.h = __builtin_amdgcn_cvt_pkrtz(a, b);
  return cv.u;
}

// ---------------------------------------------------------------------------
__global__ __launch_bounds__(256) void k_prep(
    const float* __restrict__ w1x1,  const float* __restrict__ bn1x1,
    const float* __restrict__ c1c2w, const float* __restrict__ c1bn2,
    const float* __restrict__ c1c1w, const float* __restrict__ c1bn1,
    const float* __restrict__ c1pj,  const float* __restrict__ c1bnp,
    const float* __restrict__ c2c2w, const float* __restrict__ c2bn2,
    const float* __restrict__ c2c1w, const float* __restrict__ c2bn1,
    const float* __restrict__ c2pj,  const float* __restrict__ c2bnp,
    float* __restrict__ prm)
{
  const int t = threadIdx.x;
  const float eps = 1e-5f;

  // W1eff[ds][i]: c2 conv1 + bn1 + proj + bnp folded 16->1
  for (int idx = t; idx < 144; idx += 256) {
    int ds = idx / 16, i = idx % 16;
    float spv = c2bnp[0] / sqrtf(c2bnp[3] + eps);
    float acc = 0.f;
    for (int o = 0; o < 16; ++o) {
      float s1 = c2bn1[o] / sqrtf(c2bn1[48 + o] + eps);
      acc += c2pj[o] * s1 * c2c1w[(o * 16 + i) * 9 + ds];
    }
    prm[idx] = spv * acc;
  }
  for (int i = t; i < 16; i += 256) {
    float s = c1bnp[i] / sqrtf(c1bnp[48 + i] + eps);
    prm[144 + i] = s * c1pj[i];
    prm[160 + i] = c1bnp[16 + i] - c1bnp[32 + i] * s;
  }
  for (int o = t; o < 16; o += 256) {
    float s = c2bn2[o] / sqrtf(c2bn2[48 + o] + eps);
    prm[176 + o] = s;
    prm[192 + o] = c2bn2[16 + o] - c2bn2[32 + o] * s;
  }
  for (int k = t; k < 9; k += 256) {
    prm[208 + k] = c1c2w[k];
    prm[217 + k] = c1c1w[k];
  }
  if (t == 0) {
    float S2 = c1bn2[0] / sqrtf(c1bn2[3] + eps);
    prm[226] = S2;
    prm[227] = c1bn2[1] - c1bn2[2] * S2;
    float S1 = c1bn1[0] / sqrtf(c1bn1[3] + eps);
    prm[228] = S1;
    prm[229] = c1bn1[1] - c1bn1[2] * S1;
    float spv = c2bnp[0] / sqrtf(c2bnp[3] + eps);
    float k0 = 0.f;
    for (int o = 0; o < 16; ++o) {
      float s1 = c2bn1[o] / sqrtf(c2bn1[48 + o] + eps);
      k0 += c2pj[o] * (c2bn1[16 + o] - c2bn1[32 + o] * s1);
    }
    prm[230] = spv * (k0 - c2bnp[2]) + c2bnp[1];
    prm[231] = 0.f;
  }
  // feat 1x1: wsum, scv, shv
  for (int o = t; o < 64; o += 256) {
    float s = 0.f;
    for (int c = 0; c < 640; ++c) s += w1x1[o * 640 + c];
    prm[WSUMF + o] = s;
    float scv = bn1x1[o] / sqrtf(bn1x1[192 + o] + eps);
    prm[SCVF + o] = scv;
    prm[SHVF + o] = bn1x1[64 + o] - bn1x1[128 + o] * scv;
  }
  __syncthreads();

  // PK2: conv2 A-fragments. A[m=o=lane&15][k=quad*8+j], tap=2c+(quad>>1),
  // i=(quad&1)*8+j. tap 9 = zero pad.
  _Float16* pk2 = (_Float16*)(prm + PK2F);
  for (int idx = t; idx < 2560; idx += 256) {
    int c = idx >> 9, rem = idx & 511;
    int ln = rem >> 3, j = rem & 7;
    int o = ln & 15, qq = ln >> 4;
    int tap = 2 * c + (qq >> 1);
    int i = (qq & 1) * 8 + j;
    float v = (tap < 9) ? c2c2w[(o * 16 + i) * 9 + tap] : 0.f;
    pk2[idx] = (_Float16)v;
  }
  // PK1: conv1-eff A-fragments (row m=0 only = W1eff, rest 0)
  _Float16* pk1 = (_Float16*)(prm + PK1F);
  for (int idx = t; idx < 2560; idx += 256) {
    int c = idx >> 9, rem = idx & 511;
    int ln = rem >> 3, j = rem & 7;
    int m = ln & 15, qq = ln >> 4;
    int k = c * 32 + qq * 8 + j;
    int tp = k >> 4, i = k & 15;
    float v = (m == 0 && tp < 9) ? prm[tp * 16 + i] : 0.f;
    pk1[idx] = (_Float16)v;
  }
  // PKW: feat GEMM A-frags. M=80: rows 0..63 = W, 64 = ones, 65..79 = 0.
  // frag id fi = cc*10 + mt*2 + kk ; A[m=mt*16+(lane&15)][k=cc*64+kk*32+qd*8+j]
  _Float16* pkw = (_Float16*)(prm + PKWF);
  for (int idx = t; idx < 51200; idx += 256) {
    int fi = idx >> 9, rem = idx & 511;
    int ln = rem >> 3, j = rem & 7;
    int cc = fi / 10, r2 = fi - cc * 10;
    int mt = r2 >> 1, kk = r2 & 1;
    int m = mt * 16 + (ln & 15);
    int k = cc * 64 + kk * 32 + ((ln >> 4) & 3) * 8 + j;
    float v = (m < 64) ? w1x1[m * 640 + k] : (m == 64 ? 1.f : 0.f);
    pkw[idx] = (_Float16)v;
  }
}

// ---------------------------------------------------------------------------
// Fused center + 1x1 conv (MFMA) + BN + relu + per-position L2 norm.
// Also emits XT fp16 [p][c] and position means mp. grid = 80 blocks.
// Centering via W(x-1m) = Wx - wsum*m ; m from ones-row (row 64) of A.
__global__ __launch_bounds__(256) void k_feat(
    const float* __restrict__ spt, const float* __restrict__ qry,
    float* __restrict__ ws)
{
  __shared__ __align__(16) _Float16 XTL[112 * 72];   // 16128 B, rows pad to 72
  __shared__ __align__(16) float OUT[64 * 104];      // 26624 B
  __shared__ __align__(16) float mrow[112];
  __shared__ __align__(16) float rn[112];

  const int b = blockIdx.x, t = threadIdx.x;
  const int lane = t & 63, wvv = t >> 6;
  const int n0 = lane & 15, qd = (lane >> 4) & 3;
  const float* src = (b < 5) ? spt + b * 64000 : qry + (b - 5) * 64000;
  float* dst = (b < 5) ? ws + OFF_SF + b * 6400 : ws + OFF_QF + (b - 5) * 6400;
  unsigned int* xtg = (unsigned int*)(ws + ((b < 5) ? (OFF_XTS + b * 32000)
                                                    : (OFF_XTQ + (b - 5) * 32000)));
  const float* prm = ws + OFF_PRM;
  const _Float16* pkw = (const _Float16*)(prm + PKWF);

  // zero pad rows p=100..111 (stay zero across chunks)
  for (int idx = t; idx < 12 * 36; idx += 256)
    ((unsigned int*)(XTL + 100 * 72))[idx] = 0u;

  f32x4 acc[9];
  #pragma unroll
  for (int ti = 0; ti < 9; ++ti) { acc[ti][0]=0.f; acc[ti][1]=0.f; acc[ti][2]=0.f; acc[ti][3]=0.f; }

  for (int cc = 0; cc < 10; ++cc) {
    __syncthreads();
    // stage chunk: X[cbase+2cp..+1][p] -> XTL[p][2cp..2cp+1] fp16 (c-pairs)
    for (int u = t; u < 800; u += 256) {
      int cp = u / 25, p4 = u - cp * 25;
      const float* r0 = src + (cc * 64 + 2 * cp) * 100 + p4 * 4;
      f4v a = *(const f4v*)r0;
      f4v c1 = *(const f4v*)(r0 + 100);
      #pragma unroll
      for (int e = 0; e < 4; ++e)
        *(unsigned int*)(XTL + (p4 * 4 + e) * 72 + 2 * cp) = pkrtz(a[e], c1[e]);
    }
    __syncthreads();
    // XT global write (p-major, coalesced over c)
    for (int u = t; u < 3200; u += 256) {
      int p = u >> 5, cp = u & 31;
      xtg[p * 320 + cc * 32 + cp] = *(const unsigned int*)(XTL + p * 72 + 2 * cp);
    }
    // MFMA K-steps: 35 output tiles (5 mt x 7 nt), 9 per wave (idx 34 dup'd)
    #pragma unroll
    for (int kk = 0; kk < 2; ++kk) {
      #pragma unroll
      for (int ti = 0; ti < 9; ++ti) {
        int idx = wvv + ti * 4; if (idx > 34) idx = 34;
        int mt = idx / 7, nt = idx - mt * 7;
        half8v av = *(const half8v*)(pkw + (cc * 10 + mt * 2 + kk) * 512 + lane * 8);
        half8v bv = *(const half8v*)(XTL + (nt * 16 + n0) * 72 + kk * 32 + qd * 8);
        acc[ti] = __builtin_amdgcn_mfma_f32_16x16x32_f16(av, bv, acc[ti], 0, 0, 0);
      }
    }
  }
  // mrow from ones-row (m=64): mt==4, row-in-tile 0 => qd==0, reg 0
  #pragma unroll
  for (int ti = 0; ti < 9; ++ti) {
    int idx = wvv + ti * 4; if (idx > 34) idx = 34;
    int mt = idx / 7, nt = idx - mt * 7;
    if (mt == 4 && qd == 0) {
      int p = nt * 16 + n0;
      mrow[p] = acc[ti][0] * (1.f / 640.f);
    }
  }
  __syncthreads();
  // epilogue: centering correction + BN + relu -> OUT[o][p]
  #pragma unroll
  for (int ti = 0; ti < 9; ++ti) {
    int idx = wvv + ti * 4; if (idx > 34) idx = 34;
    int mt = idx / 7, nt = idx - mt * 7;
    if (mt < 4) {
      int p = nt * 16 + n0;
      if (p < 100) {
        float mp = mrow[p];
        #pragma unroll
        for (int r = 0; r < 4; ++r) {
          int o = mt * 16 + qd * 4 + r;
          float v = acc[ti][r] - prm[WSUMF + o] * mp;
          v = prm[SCVF + o] * v + prm[SHVF + o];
          OUT[o * 104 + p] = v > 0.f ? v : 0.f;
        }
      }
    }
  }
  __syncthreads();
  if (t < 100) {
    float s = 0.f;
    for (int o = 0; o < 64; ++o) { float v = OUT[o * 104 + t]; s += v * v; }
    float nr = sqrtf(s);
    rn[t] = 1.f / (nr > 1e-8f ? nr : 1e-8f);
    ws[OFF_MP + b * 100 + t] = mrow[t];
  }
  __syncthreads();
  for (int idx = t; idx < 1600; idx += 256) {
    int o = idx / 25, pq = idx - o * 25;
    f4v v = *(const f4v*)(OUT + o * 104 + pq * 4);
    f4v r4 = *(const f4v*)(rn + pq * 4);
    #pragma unroll
    for (int e = 0; e < 4; ++e) v[e] *= r4[e];
    *(f4v*)(dst + o * 100 + pq * 4) = v;
  }
}

// ---------------------------------------------------------------------------
// qry_pooled from XT fp16 (coalesced) + mp means
__global__ __launch_bounds__(256) void k_pool(float* __restrict__ ws,
                                              float* __restrict__ out)
{
  __shared__ float mq[100];
  __shared__ float msumL;
  const int qi = blockIdx.x, t = threadIdx.x;
  if (t < 100) mq[t] = ws[OFF_MP + (5 + qi) * 100 + t];
  __syncthreads();
  if (t == 0) { float s = 0.f; for (int p = 0; p < 100; ++p) s += mq[p]; msumL = s; }
  __syncthreads();
  const unsigned int* xt = (const unsigned int*)(ws + OFF_XTQ + qi * 32000);
  const float msum = msumL;
  for (int u = t; u < 320; u += 256) {
    float s0 = 0.f, s1 = 0.f;
    for (int p = 0; p < 100; ++p) {
      union { unsigned int u; fp16x2 h; } cv;
      cv.u = xt[p * 320 + u];
      s0 += (float)cv.h[0]; s1 += (float)cv.h[1];
    }
    out[375 + qi * 640 + 2 * u]     = (s0 - msum) * 0.01f;
    out[375 + qi * 640 + 2 * u + 1] = (s1 - msum) * 0.01f;
  }
}

// ---------------------------------------------------------------------------
// Fused corr + cca branch. grid = 375 items x 2 branches. (unchanged R5)
__global__ __launch_bounds__(1024) __attribute__((amdgpu_waves_per_eu(4, 4)))
void k_cca(float* __restrict__ ws)
{
  extern __shared__ char smem[];
  _Float16* T2h = (_Float16*)smem;
  float* sfL  = (float*)(smem + 20480);
  float* qfL  = (float*)(smem + 46080);
  float* CORR = (float*)(smem + 71680);
  float* T1   = (float*)(smem + 20480);

  const float* prm = ws + OFF_PRM;
  const int bid = blockIdx.x;
  const int it = bid >> 1, br = bid & 1;
  const int q = it / 5, n = it % 5;
  const int t = threadIdx.x;
  const int lane = t & 63, wv = t >> 6;
  const int n0 = lane & 15, qd = (lane >> 4) & 3;
  const int qh = qd >> 1, ih = qd & 1;

  const _Float16* pk2 = (const _Float16*)(prm + PK2F);
  const _Float16* pk1 = (const _Float16*)(prm + PK1F);
  half8v A2[5], A1[5];
  #pragma unroll
  for (int c = 0; c < 5; ++c) {
    A2[c] = *(const half8v*)(pk2 + c * 512 + lane * 8);
    A1[c] = *(const half8v*)(pk1 + c * 512 + lane * 8);
  }
  float sc2[4], bc2[4];
  #pragma unroll
  for (int r = 0; r < 4; ++r) { sc2[r] = prm[176 + qd * 4 + r]; bc2[r] = prm[192 + qd * 4 + r]; }

  const int d1E[5] = {-1,-1, 0, 0, 1}, d2E[5] = {-1, 1, 0,-1, 1};
  const int d1O[5] = {-1, 0, 0, 1, 0}, d2O[5] = { 0,-1, 1, 0, 0};

  int D1[5];
  #pragma unroll
  for (int c = 0; c < 5; ++c)
    D1[c] = (qh ? (d1O[c] * 10 + d2O[c]) : (d1E[c] * 10 + d2E[c])) * 16;
  const int BY = Y2S + ih * Y2HALF;
  const int ihY1 = ih * Y1HALF;

  {
    const f4v* sf4 = (const f4v*)(ws + OFF_SF + n * 6400);
    const f4v* qf4 = (const f4v*)(ws + OFF_QF + q * 6400);
    f4v* sL4 = (f4v*)sfL; f4v* qL4 = (f4v*)qfL;
    for (int idx = t; idx < 1600; idx += 1024) { sL4[idx] = sf4[idx]; qL4[idx] = qf4[idx]; }
  }
  __syncthreads();

  if (t < 625) {
    const int ij0 = (t / 25) * 4, kl0 = (t % 25) * 4;
    f4v acc4[4];
    #pragma unroll
    for (int jj = 0; jj < 4; ++jj) { acc4[jj][0]=0.f; acc4[jj][1]=0.f; acc4[jj][2]=0.f; acc4[jj][3]=0.f; }
    for (int c = 0; c < 64; ++c) {
      f4v sv = *(const f4v*)(sfL + c * 100 + ij0);
      f4v qv = *(const f4v*)(qfL + c * 100 + kl0);
      #pragma unroll
      for (int jj = 0; jj < 4; ++jj)
        #pragma unroll
        for (int e = 0; e < 4; ++e) acc4[jj][e] += sv[jj] * qv[e];
    }
    if (br == 0) {
      #pragma unroll
      for (int jj = 0; jj < 4; ++jj) *(f4v*)(CORR + (ij0 + jj) * 100 + kl0) = acc4[jj];
    } else {
      #pragma unroll
      for (int kk = 0; kk < 4; ++kk) {
        f4v tr;
        #pragma unroll
        for (int jj = 0; jj < 4; ++jj) tr[jj] = acc4[jj][kk];
        *(f4v*)(CORR + (kl0 + kk) * 100 + ij0) = tr;
      }
    }
  }
  __syncthreads();

  const float S2 = prm[226], B2 = prm[227], S1 = prm[228], B1 = prm[229];

  for (int idx = t; idx < 2500; idx += 1024) {
    int f = idx / 25, sq = (idx % 25) * 4;
    int f1 = f / 10, f2 = f - f1 * 10;
    f4v acc; acc[0]=0.f; acc[1]=0.f; acc[2]=0.f; acc[3]=0.f;
    #pragma unroll
    for (int du = 0; du < 3; ++du) {
      int nf1 = f1 + du - 1;
      if ((unsigned)nf1 >= 10u) continue;
      #pragma unroll
      for (int dv = 0; dv < 3; ++dv) {
        int nf2 = f2 + dv - 1;
        if ((unsigned)nf2 >= 10u) continue;
        float w = prm[208 + du * 3 + dv];
        f4v xv = *(const f4v*)(CORR + (nf1 * 10 + nf2) * 100 + sq);
        #pragma unroll
        for (int e = 0; e < 4; ++e) acc[e] += w * xv[e];
      }
    }
    #pragma unroll
    for (int e = 0; e < 4; ++e) { float v = S2 * acc[e] + B2; acc[e] = v > 0.f ? v : 0.f; }
    *(f4v*)(T1 + f * 100 + sq) = acc;
  }
  __syncthreads();

  if (t < 1000) {
    const int f = t / 10, s1 = t - (t / 10) * 10;
    const float* rowB = T1 + f * 100;
    f4v r[3][3];
    float w[3][3];
    #pragma unroll
    for (int dh = 0; dh < 3; ++dh) {
      int rr = s1 + dh - 1;
      bool okr = (unsigned)rr < 10u;
      int rc = rr < 0 ? 0 : (rr > 9 ? 9 : rr);
      const float* rp = rowB + rc * 10;
      r[dh][0] = *(const f4v*)(rp);
      r[dh][1] = *(const f4v*)(rp + 4);
      r[dh][2] = *(const f4v*)(rp + 8);
      #pragma unroll
      for (int dw = 0; dw < 3; ++dw) w[dh][dw] = okr ? prm[217 + dh * 3 + dw] : 0.f;
    }
    float o[10];
    #pragma unroll
    for (int s2 = 0; s2 < 10; ++s2) {
      float a = 0.f;
      #pragma unroll
      for (int dh = 0; dh < 3; ++dh)
        #pragma unroll
        for (int dw = 0; dw < 3; ++dw) {
          int col = s2 + dw - 1;
          if (col < 0 || col > 9) continue;
          a += w[dh][dw] * r[dh][col >> 2][col & 3];
        }
      o[s2] = a;
    }
    unsigned int* dst = (unsigned int*)((char*)T2h + (f * 100 + s1 * 10) * 2);
    #pragma unroll
    for (int k = 0; k < 5; ++k)
      dst[k] = pkrtz(S1 * o[2 * k] + B1, S1 * o[2 * k + 1] + B1);
  }
  __syncthreads();

  #define GEN_Y1(F1N)                                                          \
    if (t < 1000) {                                                            \
      const int _sl = (F1N) % 3;                                               \
      const float t2 = (float)T2h[(F1N) * 1000 + t];                           \
      unsigned int d[8];                                                       \
      _Pragma("unroll")                                                        \
      for (int j = 0; j < 8; ++j) {                                            \
        float ya = fmaxf(prm[144 + 2 * j] * t2 + prm[160 + 2 * j], 0.f);       \
        float yb = fmaxf(prm[145 + 2 * j] * t2 + prm[161 + 2 * j], 0.f);       \
        d[j] = pkrtz(ya, yb);                                                  \
      }                                                                        \
      u32x4 lo, hi;                                                            \
      lo[0]=d[0]; lo[1]=d[1]; lo[2]=d[2]; lo[3]=d[3];                          \
      hi[0]=d[4]; hi[1]=d[5]; hi[2]=d[6]; hi[3]=d[7];                          \
      *(u32x4*)(smem + Y1S + _sl * 32000 + t * 16) = lo;                       \
      *(u32x4*)(smem + Y1S + _sl * 32000 + Y1HALF + t * 16) = hi;              \
    }

  GEN_Y1(0)
  GEN_Y1(1)
  if (t >= 1000 && t < 1004) *(unsigned int*)(smem + ZPB + (t - 1000) * 4) = 0u;
  __syncthreads();

  const float Cf = prm[230];
  float* resb = ws + (br ? OFF_RB : OFF_RA) + it * 10000;

  for (int g = 0; g < 10; ++g) {
    const int sl0 = g % 3, slP = (g + 1) % 3, slM = (g + 2) % 3;
    const int baseM = Y1S + slM * 32000;
    const int base0 = Y1S + sl0 * 32000;
    const int baseP = Y1S + slP * 32000;
    const bool okM = (g >= 1), okP = (g <= 8);
    int Bc[5]; bool v1c[5];
    #pragma unroll
    for (int c = 0; c < 5; ++c) {
      int bE = (d1E[c] < 0 ? baseM : (d1E[c] > 0 ? baseP : base0)) + d2E[c] * 1600;
      int bO = (d1O[c] < 0 ? baseM : (d1O[c] > 0 ? baseP : base0)) + d2O[c] * 1600;
      Bc[c] = (qh ? bO : bE) + ihY1;
      bool vE = d1E[c] < 0 ? okM : (d1E[c] > 0 ? okP : true);
      bool vO = (c == 4) ? false : (d1O[c] < 0 ? okM : (d1O[c] > 0 ? okP : true));
      v1c[c] = qh ? vO : vE;
    }

    for (int tile = wv; tile < 63; tile += 16) {
      const int p = tile * 16 + n0;
      const int pcp = p < 1000 ? p : 999;
      const int pp = pcp * 16;
      const int f2 = pcp / 100;
      const bool fm = f2 > 0, fp = f2 < 9;
      f32x4 acc; acc[0]=0.f; acc[1]=0.f; acc[2]=0.f; acc[3]=0.f;
      #pragma unroll
      for (int c = 0; c < 5; ++c) {
        bool v2E = d2E[c] < 0 ? fm : (d2E[c] > 0 ? fp : true);
        bool v2O = d2O[c] < 0 ? fm : (d2O[c] > 0 ? fp : true);
        bool v = v1c[c] && (qh ? v2O : v2E);
        int addr = v ? (Bc[c] + pp) : ZPB;
        half8v b = *(const half8v*)(smem + addr);
        acc = __builtin_amdgcn_mfma_f32_16x16x32_f16(A2[c], b, acc, 0, 0, 0);
      }
      float v0 = fmaxf(sc2[0] * acc[0] + bc2[0], 0.f);
      float v1 = fmaxf(sc2[1] * acc[1] + bc2[1], 0.f);
      float v2 = fmaxf(sc2[2] * acc[2] + bc2[2], 0.f);
      float v3 = fmaxf(sc2[3] * acc[3] + bc2[3], 0.f);
      u32x2 wq; wq[0] = pkrtz(v0, v1); wq[1] = pkrtz(v2, v3);
      *(u32x2*)(smem + Y2S + qh * Y2HALF + p * 16 + ih * 8) = wq;
    }
    __syncthreads();

    for (int tile = wv; tile < 63; tile += 16) {
      const int p = tile * 16 + n0;
      const int pcp = p < 1000 ? p : 999;
      const int b0 = BY + pcp * 16;
      const int f2 = pcp / 100;
      const int s = pcp - f2 * 100;
      const int s1 = s / 10, s2 = s - s1 * 10;
      const bool rm = s1 > 0, rp = s1 < 9, cm = s2 > 0, cp = s2 < 9;
      f32x4 acc; acc[0]=0.f; acc[1]=0.f; acc[2]=0.f; acc[3]=0.f;
      #pragma unroll
      for (int c = 0; c < 5; ++c) {
        bool vE = (d1E[c] < 0 ? rm : (d1E[c] > 0 ? rp : true)) &&
                  (d2E[c] < 0 ? cm : (d2E[c] > 0 ? cp : true));
        bool vO = (c == 4) ? false :
                  ((d1O[c] < 0 ? rm : (d1O[c] > 0 ? rp : true)) &&
                   (d2O[c] < 0 ? cm : (d2O[c] > 0 ? cp : true)));
        bool v = qh ? vO : vE;
        int addr = v ? (b0 + D1[c]) : ZPB;
        half8v b = *(const half8v*)(smem + addr);
        acc = __builtin_amdgcn_mfma_f32_16x16x32_f16(A1[c], b, acc, 0, 0, 0);
      }
      if (qd == 0 && p < 1000) {
        const int fg = g * 10 + f2;
        const int pos = br ? (s * 100 + fg) : (fg * 100 + s);
        resb[pos] = acc[0] + Cf;
      }
    }
    if (g + 2 <= 9) { GEN_Y1(g + 2) }
    __syncthreads();
  }
  #undef GEN_Y1
}

// ---------------------------------------------------------------------------
// per-item gaussian_normalize + softmax(/5) over each axis; attn sums
__global__ __launch_bounds__(256) void k_stats(float* __restrict__ ws)
{
  __shared__ float F[10000];
  __shared__ float mc[100], ic[100], rc[100];
  __shared__ float mr[100], ir[100], rr[100];
  const int it = blockIdx.x, t = threadIdx.x;
  const f4v* ra4 = (const f4v*)(ws + OFF_RA + it * 10000);
  const f4v* rb4 = (const f4v*)(ws + OFF_RB + it * 10000);
  f4v* F4 = (f4v*)F;
  for (int idx = t; idx < 2500; idx += 256) {
    f4v a = ra4[idx], b = rb4[idx];
    #pragma unroll
    for (int e = 0; e < 4; ++e) a[e] += b[e];
    F4[idx] = a;
  }
  __syncthreads();
  if (t < 100) {
    float s = 0.f;
    for (int ij = 0; ij < 100; ++ij) s += F[ij * 100 + t];
    float m = s * 0.01f;
    float ss = 0.f;
    for (int ij = 0; ij < 100; ++ij) { float d = F[ij * 100 + t] - m; ss += d * d; }
    float inv = 1.f / (sqrtf(ss * (1.f / 99.f) + 1e-5f) * 5.f);
    float den = 0.f;
    for (int ij = 0; ij < 100; ++ij) den += __expf((F[ij * 100 + t] - m) * inv);
    mc[t] = m; ic[t] = inv; rc[t] = 1.f / den;
  } else if (t < 200) {
    const int r = t - 100;
    float s = 0.f;
    for (int kl = 0; kl < 100; ++kl) s += F[r * 100 + kl];
    float m = s * 0.01f;
    float ss = 0.f;
    for (int kl = 0; kl < 100; ++kl) { float d = F[r * 100 + kl] - m; ss += d * d; }
    float inv = 1.f / (sqrtf(ss * (1.f / 99.f) + 1e-5f) * 5.f);
    float den = 0.f;
    for (int kl = 0; kl < 100; ++kl) den += __expf((F[r * 100 + kl] - m) * inv);
    mr[r] = m; ir[r] = inv; rr[r] = 1.f / den;
  }
  __syncthreads();
  if (t < 100) {
    float s = 0.f;
    for (int kl = 0; kl < 100; ++kl)
      s += __expf((F[t * 100 + kl] - mc[kl]) * ic[kl]) * rc[kl];
    ws[OFF_AS + it * 100 + t] = s;
  } else if (t < 200) {
    const int r = t - 100;
    float s2 = 0.f;
    for (int ij = 0; ij < 100; ++ij)
      s2 += __expf((F[ij * 100 + r] - mr[ij]) * ir[ij]) * rr[ij];
    ws[OFF_AQ + it * 100 + r] = s2;
  }
}

// ---------------------------------------------------------------------------
// attention pooling + cosine similarity from XT fp16 (coalesced) + mp
__global__ __launch_bounds__(256) void k_sim(float* __restrict__ ws, float* __restrict__ out)
{
  __shared__ float asL[100], aqL[100], msL[100], mqL[100];
  __shared__ float alph[2];
  __shared__ float red[12];
  const int it = blockIdx.x, t = threadIdx.x;
  const int q = it / 5, n = it % 5;
  if (t < 100) {
    asL[t] = ws[OFF_AS + it * 100 + t];
    aqL[t] = ws[OFF_AQ + it * 100 + t];
    msL[t] = ws[OFF_MP + n * 100 + t];
    mqL[t] = ws[OFF_MP + (5 + q) * 100 + t];
  }
  __syncthreads();
  if (t < 2) {
    float s = 0.f;
    for (int p = 0; p < 100; ++p) s += t ? (aqL[p] * mqL[p]) : (asL[p] * msL[p]);
    alph[t] = s;
  }
  __syncthreads();
  const unsigned int* xs = (const unsigned int*)(ws + OFF_XTS + n * 32000);
  const unsigned int* xq = (const unsigned int*)(ws + OFF_XTQ + q * 32000);
  const float als = alph[0], alq = alph[1];
  float dot = 0.f, na = 0.f, nb = 0.f;
  for (int u = t; u < 320; u += 256) {
    float s0 = 0.f, s1 = 0.f, q0 = 0.f, q1 = 0.f;
    for (int p = 0; p < 100; ++p) {
      union { unsigned int u; fp16x2 h; } a, bq;
      a.u = xs[p * 320 + u];
      bq.u = xq[p * 320 + u];
      float ap = asL[p], qp = aqL[p];
      s0 += ap * (float)a.h[0]; s1 += ap * (float)a.h[1];
      q0 += qp * (float)bq.h[0]; q1 += qp * (float)bq.h[1];
    }
    float sa0 = (s0 - als) * 0.01f, sa1 = (s1 - als) * 0.01f;
    float qa0 = (q0 - alq) * 0.01f, qa1 = (q1 - alq) * 0.01f;
    dot += sa0 * qa0 + sa1 * qa1;
    na  += sa0 * sa0 + sa1 * sa1;
    nb  += qa0 * qa0 + qa1 * qa1;
  }
  #pragma unroll
  for (int off = 32; off > 0; off >>= 1) {
    dot += __shfl_down(dot, off);
    na  += __shfl_down(na, off);
    nb  += __shfl_down(nb, off);
  }
  const int wid = t >> 6, lanei = t & 63;
  if (lanei == 0) { red[wid * 3 + 0] = dot; red[wid * 3 + 1] = na; red[wid * 3 + 2] = nb; }
  __syncthreads();
  if (t == 0) {
    dot = red[0] + red[3] + red[6] + red[9];
    na  = red[1] + red[4] + red[7] + red[10];
    nb  = red[2] + red[5] + red[8] + red[11];
    float ns = sqrtf(na); ns = ns > 1e-8f ? ns : 1e-8f;
    float nq2 = sqrtf(nb); nq2 = nq2 > 1e-8f ? nq2 : 1e-8f;
    out[it] = dot / (ns * nq2) * 5.f;   // /TEMPERATURE(0.2)
  }
}

// ---------------------------------------------------------------------------
extern "C" void kernel_launch(void* const* d_in, const int* in_sizes, int n_in,
                              void* d_out, int out_size, void* d_ws, size_t ws_size,
                              hipStream_t stream)
{
  (void)in_sizes; (void)n_in; (void)out_size; (void)ws_size;
  const float* spt    = (const float*)d_in[0];
  const float* qry    = (const float*)d_in[1];
  const float* w1x1   = (const float*)d_in[2];
  const float* bn1x1  = (const float*)d_in[3];
  const float* c1c2w  = (const float*)d_in[4];
  const float* c1bn2  = (const float*)d_in[5];
  const float* c1c1w  = (const float*)d_in[6];
  const float* c1bn1  = (const float*)d_in[7];
  const float* c1pj   = (const float*)d_in[8];
  const float* c1bnp  = (const float*)d_in[9];
  const float* c2c2w  = (const float*)d_in[10];
  const float* c2bn2  = (const float*)d_in[11];
  const float* c2c1w  = (const float*)d_in[12];
  const float* c2bn1  = (const float*)d_in[13];
  const float* c2pj   = (const float*)d_in[14];
  const float* c2bnp  = (const float*)d_in[15];
  float* ws  = (float*)d_ws;
  float* out = (float*)d_out;

  k_prep<<<1, 256, 0, stream>>>(w1x1, bn1x1,
                                c1c2w, c1bn2, c1c1w, c1bn1, c1pj, c1bnp,
                                c2c2w, c2bn2, c2c1w, c2bn1, c2pj, c2bnp,
                                ws + OFF_PRM);
  k_feat<<<80, 256, 0, stream>>>(spt, qry, ws);
  k_pool<<<75, 256, 0, stream>>>(ws, out);

  (void)hipFuncSetAttribute((const void*)k_cca,
                            hipFuncAttributeMaxDynamicSharedMemorySize, LDS_TOTAL);
  k_cca<<<NITEM * 2, 1024, LDS_TOTAL, stream>>>(ws);

  k_stats<<<NITEM, 256, 0, stream>>>(ws);
  k_sim<<<NITEM, 256, 0, stream>>>(ws, out);
}

// Round 7
// 358.985 us; speedup vs baseline: 8.2644x; 1.1566x over previous
//
#include <hip/hip_runtime.h>

// ---------------------------------------------------------------------------
// CCALayer: spt (1,5,640,10,10)  qry (75,640,10,10)
// Q=75, way=5, C=640, Cf=64, P=100 (10x10), items=375
// Output: sim (75,5) [375] ++ qry_pooled (75,640) [48000]
// ---------------------------------------------------------------------------

#define NITEM 375

// ws layout (float offsets)
#define OFF_XTS 0            // raw support transposed fp16 [5][100 p][640 c]
#define OFF_XTQ 160000       // raw query transposed fp16 [75][100][640]
#define OFF_MP  2560000      // per-image position means [80][100] f32
#define OFF_SF  2568000      // sf  5*64*100 f32 [c][p]
#define OFF_QF  2600000      // qf 75*64*100
#define OFF_RA  3080000      // branch-A result 375*10000
#define OFF_RB  6830000      // branch-B result 375*10000
#define OFF_PRM 10655000     // folded params

// prm layout (floats):
// [0..143] W1eff[ds][i]; [144..159] Av; [160..175] Bp
// [176..191] S2c2; [192..207] B2c2
// [208..216] w2c1; [217..225] w1c1
// [226] S2 [227] B2 [228] S1 [229] B1 [230] Cf
// PK2 (conv2 A-frags, 2560 fp16) at floats [232,1512)
// PK1 (conv1eff A-frags, 2560 fp16) at floats [1512,2792)
// WSUM [2792,2856) ; SCV [2856,2920) ; SHV [2920,2984)
// PKW (feat GEMM A-frags, 51200 fp16) at floats [2984,28584)
#define PK2F 232
#define PK1F 1512
#define WSUMF 2792
#define SCVF 2856
#define SHVF 2920
#define PKWF 2984

// k_cca LDS byte map (dynamic, 148768 total)
#define Y1S   20480
#define Y1HALF 16000
#define ZPB   116480
#define Y2S   116512
#define Y2HALF 16128
#define LDS_TOTAL 148768

typedef float f4v __attribute__((ext_vector_type(4)));
typedef float f32x4 __attribute__((ext_vector_type(4)));
typedef _Float16 half8v __attribute__((ext_vector_type(8)));
typedef __fp16 fp16x2 __attribute__((ext_vector_type(2)));
typedef unsigned int u32x4 __attribute__((ext_vector_type(4)));
typedef unsigned int u32x2 __attribute__((ext_vector_type(2)));

__device__ __forceinline__ unsigned int pkrtz(float a, float b) {
  union { fp16x2 h; unsigned int u; } cv;
  cv.h = __builtin_amdgcn_cvt_pkrtz(a, b);
  return cv.u;
}

// ---------------------------------------------------------------------------
__global__ __launch_bounds__(256) void k_prep(
    const float* __restrict__ w1x1,  const float* __restrict__ bn1x1,
    const float* __restrict__ c1c2w, const float* __restrict__ c1bn2,
    const float* __restrict__ c1c1w, const float* __restrict__ c1bn1,
    const float* __restrict__ c1pj,  const float* __restrict__ c1bnp,
    const float* __restrict__ c2c2w, const float* __restrict__ c2bn2,
    const float* __restrict__ c2c1w, const float* __restrict__ c2bn1,
    const float* __restrict__ c2pj,  const float* __restrict__ c2bnp,
    float* __restrict__ prm)
{
  const int t = threadIdx.x;
  const float eps = 1e-5f;

  for (int idx = t; idx < 144; idx += 256) {
    int ds = idx / 16, i = idx % 16;
    float spv = c2bnp[0] / sqrtf(c2bnp[3] + eps);
    float acc = 0.f;
    for (int o = 0; o < 16; ++o) {
      float s1 = c2bn1[o] / sqrtf(c2bn1[48 + o] + eps);
      acc += c2pj[o] * s1 * c2c1w[(o * 16 + i) * 9 + ds];
    }
    prm[idx] = spv * acc;
  }
  for (int i = t; i < 16; i += 256) {
    float s = c1bnp[i] / sqrtf(c1bnp[48 + i] + eps);
    prm[144 + i] = s * c1pj[i];
    prm[160 + i] = c1bnp[16 + i] - c1bnp[32 + i] * s;
  }
  for (int o = t; o < 16; o += 256) {
    float s = c2bn2[o] / sqrtf(c2bn2[48 + o] + eps);
    prm[176 + o] = s;
    prm[192 + o] = c2bn2[16 + o] - c2bn2[32 + o] * s;
  }
  for (int k = t; k < 9; k += 256) {
    prm[208 + k] = c1c2w[k];
    prm[217 + k] = c1c1w[k];
  }
  if (t == 0) {
    float S2 = c1bn2[0] / sqrtf(c1bn2[3] + eps);
    prm[226] = S2;
    prm[227] = c1bn2[1] - c1bn2[2] * S2;
    float S1 = c1bn1[0] / sqrtf(c1bn1[3] + eps);
    prm[228] = S1;
    prm[229] = c1bn1[1] - c1bn1[2] * S1;
    float spv = c2bnp[0] / sqrtf(c2bnp[3] + eps);
    float k0 = 0.f;
    for (int o = 0; o < 16; ++o) {
      float s1 = c2bn1[o] / sqrtf(c2bn1[48 + o] + eps);
      k0 += c2pj[o] * (c2bn1[16 + o] - c2bn1[32 + o] * s1);
    }
    prm[230] = spv * (k0 - c2bnp[2]) + c2bnp[1];
    prm[231] = 0.f;
  }
  for (int o = t; o < 64; o += 256) {
    float s = 0.f;
    for (int c = 0; c < 640; ++c) s += w1x1[o * 640 + c];
    prm[WSUMF + o] = s;
    float scv = bn1x1[o] / sqrtf(bn1x1[192 + o] + eps);
    prm[SCVF + o] = scv;
    prm[SHVF + o] = bn1x1[64 + o] - bn1x1[128 + o] * scv;
  }
  __syncthreads();

  _Float16* pk2 = (_Float16*)(prm + PK2F);
  for (int idx = t; idx < 2560; idx += 256) {
    int c = idx >> 9, rem = idx & 511;
    int ln = rem >> 3, j = rem & 7;
    int o = ln & 15, qq = ln >> 4;
    int tap = 2 * c + (qq >> 1);
    int i = (qq & 1) * 8 + j;
    float v = (tap < 9) ? c2c2w[(o * 16 + i) * 9 + tap] : 0.f;
    pk2[idx] = (_Float16)v;
  }
  _Float16* pk1 = (_Float16*)(prm + PK1F);
  for (int idx = t; idx < 2560; idx += 256) {
    int c = idx >> 9, rem = idx & 511;
    int ln = rem >> 3, j = rem & 7;
    int m = ln & 15, qq = ln >> 4;
    int k = c * 32 + qq * 8 + j;
    int tp = k >> 4, i = k & 15;
    float v = (m == 0 && tp < 9) ? prm[tp * 16 + i] : 0.f;
    pk1[idx] = (_Float16)v;
  }
}

// ---------------------------------------------------------------------------
// PKW packing, parallel (no dependency on folded params). grid = 64 blocks.
// frag id fi = cc*10 + mt*2 + kk ; A[m=mt*16+(lane&15)][k=cc*64+kk*32+qd*8+j]
__global__ __launch_bounds__(256) void k_prepw(
    const float* __restrict__ w1x1, float* __restrict__ prm)
{
  _Float16* pkw = (_Float16*)(prm + PKWF);
  const int base = blockIdx.x * 800;
  for (int r = threadIdx.x; r < 800; r += 256) {
    int idx = base + r;
    int fi = idx >> 9, rem = idx & 511;
    int ln = rem >> 3, j = rem & 7;
    int cc = fi / 10, r2 = fi - cc * 10;
    int mt = r2 >> 1, kk = r2 & 1;
    int m = mt * 16 + (ln & 15);
    int k = cc * 64 + kk * 32 + ((ln >> 4) & 3) * 8 + j;
    float v = (m < 64) ? w1x1[m * 640 + k] : (m == 64 ? 1.f : 0.f);
    pkw[idx] = (_Float16)v;
  }
}

// ---------------------------------------------------------------------------
// Fused center + 1x1 conv (MFMA) + BN + relu + L2 norm + XT emit + qry_pooled.
// grid = 80 blocks x 512 threads (2 waves/SIMD for latency hiding).
__global__ __launch_bounds__(512) void k_feat(
    const float* __restrict__ spt, const float* __restrict__ qry,
    float* __restrict__ ws, float* __restrict__ out)
{
  __shared__ __align__(16) _Float16 XTL[112 * 72];   // 16128 B
  __shared__ __align__(16) float OUT[64 * 104];      // 26624 B
  __shared__ __align__(16) float mrow[112];
  __shared__ __align__(16) float rn[112];
  __shared__ float CS[512];
  __shared__ float RS[640];
  __shared__ float msumL;

  const int b = blockIdx.x, t = threadIdx.x;
  const int lane = t & 63, wvv = t >> 6;             // 8 waves
  const int n0 = lane & 15, qd = (lane >> 4) & 3;
  const float* src = (b < 5) ? spt + b * 64000 : qry + (b - 5) * 64000;
  float* dst = (b < 5) ? ws + OFF_SF + b * 6400 : ws + OFF_QF + (b - 5) * 6400;
  unsigned int* xtg = (unsigned int*)(ws + ((b < 5) ? (OFF_XTS + b * 32000)
                                                    : (OFF_XTQ + (b - 5) * 32000)));
  const float* prm = ws + OFF_PRM;
  const _Float16* pkw = (const _Float16*)(prm + PKWF);

  // zero pad rows p=100..111
  for (int idx = t; idx < 12 * 36; idx += 512)
    ((unsigned int*)(XTL + 100 * 72))[idx] = 0u;

  // pooled-sum thread mapping
  const int chp = t >> 3, part = t & 7;
  const int pLo = part * 13, pHi = (pLo + 13 < 100) ? pLo + 13 : 100;

  f32x4 acc[5];
  #pragma unroll
  for (int ti = 0; ti < 5; ++ti) { acc[ti][0]=0.f; acc[ti][1]=0.f; acc[ti][2]=0.f; acc[ti][3]=0.f; }

  for (int cc = 0; cc < 10; ++cc) {
    __syncthreads();
    // stage chunk: X[cbase+2cp..+1][p] -> XTL[p][2cp..2cp+1] fp16
    for (int u = t; u < 800; u += 512) {
      int cp = u / 25, p4 = u - cp * 25;
      const float* r0 = src + (cc * 64 + 2 * cp) * 100 + p4 * 4;
      f4v a = *(const f4v*)r0;
      f4v c1 = *(const f4v*)(r0 + 100);
      #pragma unroll
      for (int e = 0; e < 4; ++e)
        *(unsigned int*)(XTL + (p4 * 4 + e) * 72 + 2 * cp) = pkrtz(a[e], c1[e]);
    }
    __syncthreads();
    // XT global write (p-major, coalesced over c)
    for (int u = t; u < 3200; u += 512) {
      int p = u >> 5, cp = u & 31;
      xtg[p * 320 + cc * 32 + cp] = *(const unsigned int*)(XTL + p * 72 + 2 * cp);
    }
    // MFMA: 35 tiles (5 mt x 7 nt), 5 per wave (idx>34 dup'd onto 34)
    #pragma unroll
    for (int kk = 0; kk < 2; ++kk) {
      #pragma unroll
      for (int ti = 0; ti < 5; ++ti) {
        int idx = wvv + ti * 8; if (idx > 34) idx = 34;
        int mt = idx / 7, nt = idx - mt * 7;
        half8v av = *(const half8v*)(pkw + (cc * 10 + mt * 2 + kk) * 512 + lane * 8);
        half8v bv = *(const half8v*)(XTL + (nt * 16 + n0) * 72 + kk * 32 + qd * 8);
        acc[ti] = __builtin_amdgcn_mfma_f32_16x16x32_f16(av, bv, acc[ti], 0, 0, 0);
      }
    }
    // per-channel sums for qry_pooled (channels cc*64 + chp)
    {
      float s = 0.f;
      for (int p = pLo; p < pHi; ++p) s += (float)XTL[p * 72 + chp];
      CS[t] = s;
    }
    __syncthreads();
    if (t < 64) {
      float s = 0.f;
      #pragma unroll
      for (int k = 0; k < 8; ++k) s += CS[t * 8 + k];
      RS[cc * 64 + t] = s;
    }
  }
  // mrow from ones-row (m=64): mt==4, qd==0, reg 0
  #pragma unroll
  for (int ti = 0; ti < 5; ++ti) {
    int idx = wvv + ti * 8; if (idx > 34) idx = 34;
    int mt = idx / 7, nt = idx - mt * 7;
    if (mt == 4 && qd == 0) {
      int p = nt * 16 + n0;
      mrow[p] = acc[ti][0] * (1.f / 640.f);
    }
  }
  __syncthreads();
  if (t == 0) { float s = 0.f; for (int p = 0; p < 100; ++p) s += mrow[p]; msumL = s; }
  // epilogue: centering correction + BN + relu -> OUT[o][p]
  #pragma unroll
  for (int ti = 0; ti < 5; ++ti) {
    int idx = wvv + ti * 8; if (idx > 34) idx = 34;
    int mt = idx / 7, nt = idx - mt * 7;
    if (mt < 4) {
      int p = nt * 16 + n0;
      if (p < 100) {
        float mp = mrow[p];
        #pragma unroll
        for (int r = 0; r < 4; ++r) {
          int o = mt * 16 + qd * 4 + r;
          float v = acc[ti][r] - prm[WSUMF + o] * mp;
          v = prm[SCVF + o] * v + prm[SHVF + o];
          OUT[o * 104 + p] = v > 0.f ? v : 0.f;
        }
      }
    }
  }
  __syncthreads();
  if (t < 100) {
    float s = 0.f;
    for (int o = 0; o < 64; ++o) { float v = OUT[o * 104 + t]; s += v * v; }
    float nr = sqrtf(s);
    rn[t] = 1.f / (nr > 1e-8f ? nr : 1e-8f);
    ws[OFF_MP + b * 100 + t] = mrow[t];
  }
  __syncthreads();
  for (int idx = t; idx < 1600; idx += 512) {
    int o = idx / 25, pq = idx - o * 25;
    f4v v = *(const f4v*)(OUT + o * 104 + pq * 4);
    f4v r4 = *(const f4v*)(rn + pq * 4);
    #pragma unroll
    for (int e = 0; e < 4; ++e) v[e] *= r4[e];
    *(f4v*)(dst + o * 100 + pq * 4) = v;
  }
  if (b >= 5) {
    const float msum = msumL;
    for (int gc = t; gc < 640; gc += 512)
      out[375 + (b - 5) * 640 + gc] = (RS[gc] - msum) * 0.01f;
  }
}

// ---------------------------------------------------------------------------
// Fused corr + cca branch. grid = 375 items x 2 branches. (unchanged R5)
__global__ __launch_bounds__(1024) __attribute__((amdgpu_waves_per_eu(4, 4)))
void k_cca(float* __restrict__ ws)
{
  extern __shared__ char smem[];
  _Float16* T2h = (_Float16*)smem;
  float* sfL  = (float*)(smem + 20480);
  float* qfL  = (float*)(smem + 46080);
  float* CORR = (float*)(smem + 71680);
  float* T1   = (float*)(smem + 20480);

  const float* prm = ws + OFF_PRM;
  const int bid = blockIdx.x;
  const int it = bid >> 1, br = bid & 1;
  const int q = it / 5, n = it % 5;
  const int t = threadIdx.x;
  const int lane = t & 63, wv = t >> 6;
  const int n0 = lane & 15, qd = (lane >> 4) & 3;
  const int qh = qd >> 1, ih = qd & 1;

  const _Float16* pk2 = (const _Float16*)(prm + PK2F);
  const _Float16* pk1 = (const _Float16*)(prm + PK1F);
  half8v A2[5], A1[5];
  #pragma unroll
  for (int c = 0; c < 5; ++c) {
    A2[c] = *(const half8v*)(pk2 + c * 512 + lane * 8);
    A1[c] = *(const half8v*)(pk1 + c * 512 + lane * 8);
  }
  float sc2[4], bc2[4];
  #pragma unroll
  for (int r = 0; r < 4; ++r) { sc2[r] = prm[176 + qd * 4 + r]; bc2[r] = prm[192 + qd * 4 + r]; }

  const int d1E[5] = {-1,-1, 0, 0, 1}, d2E[5] = {-1, 1, 0,-1, 1};
  const int d1O[5] = {-1, 0, 0, 1, 0}, d2O[5] = { 0,-1, 1, 0, 0};

  int D1[5];
  #pragma unroll
  for (int c = 0; c < 5; ++c)
    D1[c] = (qh ? (d1O[c] * 10 + d2O[c]) : (d1E[c] * 10 + d2E[c])) * 16;
  const int BY = Y2S + ih * Y2HALF;
  const int ihY1 = ih * Y1HALF;

  {
    const f4v* sf4 = (const f4v*)(ws + OFF_SF + n * 6400);
    const f4v* qf4 = (const f4v*)(ws + OFF_QF + q * 6400);
    f4v* sL4 = (f4v*)sfL; f4v* qL4 = (f4v*)qfL;
    for (int idx = t; idx < 1600; idx += 1024) { sL4[idx] = sf4[idx]; qL4[idx] = qf4[idx]; }
  }
  __syncthreads();

  if (t < 625) {
    const int ij0 = (t / 25) * 4, kl0 = (t % 25) * 4;
    f4v acc4[4];
    #pragma unroll
    for (int jj = 0; jj < 4; ++jj) { acc4[jj][0]=0.f; acc4[jj][1]=0.f; acc4[jj][2]=0.f; acc4[jj][3]=0.f; }
    for (int c = 0; c < 64; ++c) {
      f4v sv = *(const f4v*)(sfL + c * 100 + ij0);
      f4v qv = *(const f4v*)(qfL + c * 100 + kl0);
      #pragma unroll
      for (int jj = 0; jj < 4; ++jj)
        #pragma unroll
        for (int e = 0; e < 4; ++e) acc4[jj][e] += sv[jj] * qv[e];
    }
    if (br == 0) {
      #pragma unroll
      for (int jj = 0; jj < 4; ++jj) *(f4v*)(CORR + (ij0 + jj) * 100 + kl0) = acc4[jj];
    } else {
      #pragma unroll
      for (int kk = 0; kk < 4; ++kk) {
        f4v tr;
        #pragma unroll
        for (int jj = 0; jj < 4; ++jj) tr[jj] = acc4[jj][kk];
        *(f4v*)(CORR + (kl0 + kk) * 100 + ij0) = tr;
      }
    }
  }
  __syncthreads();

  const float S2 = prm[226], B2 = prm[227], S1 = prm[228], B1 = prm[229];

  for (int idx = t; idx < 2500; idx += 1024) {
    int f = idx / 25, sq = (idx % 25) * 4;
    int f1 = f / 10, f2 = f - f1 * 10;
    f4v acc; acc[0]=0.f; acc[1]=0.f; acc[2]=0.f; acc[3]=0.f;
    #pragma unroll
    for (int du = 0; du < 3; ++du) {
      int nf1 = f1 + du - 1;
      if ((unsigned)nf1 >= 10u) continue;
      #pragma unroll
      for (int dv = 0; dv < 3; ++dv) {
        int nf2 = f2 + dv - 1;
        if ((unsigned)nf2 >= 10u) continue;
        float w = prm[208 + du * 3 + dv];
        f4v xv = *(const f4v*)(CORR + (nf1 * 10 + nf2) * 100 + sq);
        #pragma unroll
        for (int e = 0; e < 4; ++e) acc[e] += w * xv[e];
      }
    }
    #pragma unroll
    for (int e = 0; e < 4; ++e) { float v = S2 * acc[e] + B2; acc[e] = v > 0.f ? v : 0.f; }
    *(f4v*)(T1 + f * 100 + sq) = acc;
  }
  __syncthreads();

  if (t < 1000) {
    const int f = t / 10, s1 = t - (t / 10) * 10;
    const float* rowB = T1 + f * 100;
    f4v r[3][3];
    float w[3][3];
    #pragma unroll
    for (int dh = 0; dh < 3; ++dh) {
      int rr = s1 + dh - 1;
      bool okr = (unsigned)rr < 10u;
      int rc = rr < 0 ? 0 : (rr > 9 ? 9 : rr);
      const float* rp = rowB + rc * 10;
      r[dh][0] = *(const f4v*)(rp);
      r[dh][1] = *(const f4v*)(rp + 4);
      r[dh][2] = *(const f4v*)(rp + 8);
      #pragma unroll
      for (int dw = 0; dw < 3; ++dw) w[dh][dw] = okr ? prm[217 + dh * 3 + dw] : 0.f;
    }
    float o[10];
    #pragma unroll
    for (int s2 = 0; s2 < 10; ++s2) {
      float a = 0.f;
      #pragma unroll
      for (int dh = 0; dh < 3; ++dh)
        #pragma unroll
        for (int dw = 0; dw < 3; ++dw) {
          int col = s2 + dw - 1;
          if (col < 0 || col > 9) continue;
          a += w[dh][dw] * r[dh][col >> 2][col & 3];
        }
      o[s2] = a;
    }
    unsigned int* dst = (unsigned int*)((char*)T2h + (f * 100 + s1 * 10) * 2);
    #pragma unroll
    for (int k = 0; k < 5; ++k)
      dst[k] = pkrtz(S1 * o[2 * k] + B1, S1 * o[2 * k + 1] + B1);
  }
  __syncthreads();

  #define GEN_Y1(F1N)                                                          \
    if (t < 1000) {                                                            \
      const int _sl = (F1N) % 3;                                               \
      const float t2 = (float)T2h[(F1N) * 1000 + t];                           \
      unsigned int d[8];                                                       \
      _Pragma("unroll")                                                        \
      for (int j = 0; j < 8; ++j) {                                            \
        float ya = fmaxf(prm[144 + 2 * j] * t2 + prm[160 + 2 * j], 0.f);       \
        float yb = fmaxf(prm[145 + 2 * j] * t2 + prm[161 + 2 * j], 0.f);       \
        d[j] = pkrtz(ya, yb);                                                  \
      }                                                                        \
      u32x4 lo, hi;                                                            \
      lo[0]=d[0]; lo[1]=d[1]; lo[2]=d[2]; lo[3]=d[3];                          \
      hi[0]=d[4]; hi[1]=d[5]; hi[2]=d[6]; hi[3]=d[7];                          \
      *(u32x4*)(smem + Y1S + _sl * 32000 + t * 16) = lo;                       \
      *(u32x4*)(smem + Y1S + _sl * 32000 + Y1HALF + t * 16) = hi;              \
    }

  GEN_Y1(0)
  GEN_Y1(1)
  if (t >= 1000 && t < 1004) *(unsigned int*)(smem + ZPB + (t - 1000) * 4) = 0u;
  __syncthreads();

  const float Cf = prm[230];
  float* resb = ws + (br ? OFF_RB : OFF_RA) + it * 10000;

  for (int g = 0; g < 10; ++g) {
    const int sl0 = g % 3, slP = (g + 1) % 3, slM = (g + 2) % 3;
    const int baseM = Y1S + slM * 32000;
    const int base0 = Y1S + sl0 * 32000;
    const int baseP = Y1S + slP * 32000;
    const bool okM = (g >= 1), okP = (g <= 8);
    int Bc[5]; bool v1c[5];
    #pragma unroll
    for (int c = 0; c < 5; ++c) {
      int bE = (d1E[c] < 0 ? baseM : (d1E[c] > 0 ? baseP : base0)) + d2E[c] * 1600;
      int bO = (d1O[c] < 0 ? baseM : (d1O[c] > 0 ? baseP : base0)) + d2O[c] * 1600;
      Bc[c] = (qh ? bO : bE) + ihY1;
      bool vE = d1E[c] < 0 ? okM : (d1E[c] > 0 ? okP : true);
      bool vO = (c == 4) ? false : (d1O[c] < 0 ? okM : (d1O[c] > 0 ? okP : true));
      v1c[c] = qh ? vO : vE;
    }

    for (int tile = wv; tile < 63; tile += 16) {
      const int p = tile * 16 + n0;
      const int pcp = p < 1000 ? p : 999;
      const int pp = pcp * 16;
      const int f2 = pcp / 100;
      const bool fm = f2 > 0, fp = f2 < 9;
      f32x4 acc; acc[0]=0.f; acc[1]=0.f; acc[2]=0.f; acc[3]=0.f;
      #pragma unroll
      for (int c = 0; c < 5; ++c) {
        bool v2E = d2E[c] < 0 ? fm : (d2E[c] > 0 ? fp : true);
        bool v2O = d2O[c] < 0 ? fm : (d2O[c] > 0 ? fp : true);
        bool v = v1c[c] && (qh ? v2O : v2E);
        int addr = v ? (Bc[c] + pp) : ZPB;
        half8v b = *(const half8v*)(smem + addr);
        acc = __builtin_amdgcn_mfma_f32_16x16x32_f16(A2[c], b, acc, 0, 0, 0);
      }
      float v0 = fmaxf(sc2[0] * acc[0] + bc2[0], 0.f);
      float v1 = fmaxf(sc2[1] * acc[1] + bc2[1], 0.f);
      float v2 = fmaxf(sc2[2] * acc[2] + bc2[2], 0.f);
      float v3 = fmaxf(sc2[3] * acc[3] + bc2[3], 0.f);
      u32x2 wq; wq[0] = pkrtz(v0, v1); wq[1] = pkrtz(v2, v3);
      *(u32x2*)(smem + Y2S + qh * Y2HALF + p * 16 + ih * 8) = wq;
    }
    __syncthreads();

    for (int tile = wv; tile < 63; tile += 16) {
      const int p = tile * 16 + n0;
      const int pcp = p < 1000 ? p : 999;
      const int b0 = BY + pcp * 16;
      const int f2 = pcp / 100;
      const int s = pcp - f2 * 100;
      const int s1 = s / 10, s2 = s - s1 * 10;
      const bool rm = s1 > 0, rp = s1 < 9, cm = s2 > 0, cp = s2 < 9;
      f32x4 acc; acc[0]=0.f; acc[1]=0.f; acc[2]=0.f; acc[3]=0.f;
      #pragma unroll
      for (int c = 0; c < 5; ++c) {
        bool vE = (d1E[c] < 0 ? rm : (d1E[c] > 0 ? rp : true)) &&
                  (d2E[c] < 0 ? cm : (d2E[c] > 0 ? cp : true));
        bool vO = (c == 4) ? false :
                  ((d1O[c] < 0 ? rm : (d1O[c] > 0 ? rp : true)) &&
                   (d2O[c] < 0 ? cm : (d2O[c] > 0 ? cp : true)));
        bool v = qh ? vO : vE;
        int addr = v ? (b0 + D1[c]) : ZPB;
        half8v b = *(const half8v*)(smem + addr);
        acc = __builtin_amdgcn_mfma_f32_16x16x32_f16(A1[c], b, acc, 0, 0, 0);
      }
      if (qd == 0 && p < 1000) {
        const int fg = g * 10 + f2;
        const int pos = br ? (s * 100 + fg) : (fg * 100 + s);
        resb[pos] = acc[0] + Cf;
      }
    }
    if (g + 2 <= 9) { GEN_Y1(g + 2) }
    __syncthreads();
  }
  #undef GEN_Y1
}

// ---------------------------------------------------------------------------
// Fused stats (gaussian_normalize + softmax + attn sums) + attention pooling
// + cosine similarity. grid = 375 items.
__global__ __launch_bounds__(256) void k_post(float* __restrict__ ws,
                                              float* __restrict__ out)
{
  __shared__ float F[10000];
  __shared__ float mc[100], ic[100], rc[100];
  __shared__ float mr[100], ir[100], rr[100];
  __shared__ float asL[100], aqL[100], msL[100], mqL[100];
  __shared__ float alph[2];
  __shared__ float red[12];
  const int it = blockIdx.x, t = threadIdx.x;
  const int q = it / 5, n = it % 5;

  const f4v* ra4 = (const f4v*)(ws + OFF_RA + it * 10000);
  const f4v* rb4 = (const f4v*)(ws + OFF_RB + it * 10000);
  f4v* F4 = (f4v*)F;
  for (int idx = t; idx < 2500; idx += 256) {
    f4v a = ra4[idx], b = rb4[idx];
    #pragma unroll
    for (int e = 0; e < 4; ++e) a[e] += b[e];
    F4[idx] = a;
  }
  if (t < 100) msL[t] = ws[OFF_MP + n * 100 + t];
  else if (t < 200) mqL[t - 100] = ws[OFF_MP + (5 + q) * 100 + t - 100];
  __syncthreads();

  if (t < 100) {
    float s = 0.f;
    for (int ij = 0; ij < 100; ++ij) s += F[ij * 100 + t];
    float m = s * 0.01f;
    float ss = 0.f;
    for (int ij = 0; ij < 100; ++ij) { float d = F[ij * 100 + t] - m; ss += d * d; }
    float inv = 1.f / (sqrtf(ss * (1.f / 99.f) + 1e-5f) * 5.f);
    float den = 0.f;
    for (int ij = 0; ij < 100; ++ij) den += __expf((F[ij * 100 + t] - m) * inv);
    mc[t] = m; ic[t] = inv; rc[t] = 1.f / den;
  } else if (t < 200) {
    const int r = t - 100;
    float s = 0.f;
    for (int kl = 0; kl < 100; ++kl) s += F[r * 100 + kl];
    float m = s * 0.01f;
    float ss = 0.f;
    for (int kl = 0; kl < 100; ++kl) { float d = F[r * 100 + kl] - m; ss += d * d; }
    float inv = 1.f / (sqrtf(ss * (1.f / 99.f) + 1e-5f) * 5.f);
    float den = 0.f;
    for (int kl = 0; kl < 100; ++kl) den += __expf((F[r * 100 + kl] - m) * inv);
    mr[r] = m; ir[r] = inv; rr[r] = 1.f / den;
  }
  __syncthreads();
  if (t < 100) {
    float s = 0.f;
    for (int kl = 0; kl < 100; ++kl)
      s += __expf((F[t * 100 + kl] - mc[kl]) * ic[kl]) * rc[kl];
    asL[t] = s;
  } else if (t < 200) {
    const int r = t - 100;
    float s2 = 0.f;
    for (int ij = 0; ij < 100; ++ij)
      s2 += __expf((F[ij * 100 + r] - mr[ij]) * ir[ij]) * rr[ij];
    aqL[r] = s2;
  }
  __syncthreads();
  if (t < 2) {
    float s = 0.f;
    for (int p = 0; p < 100; ++p) s += t ? (aqL[p] * mqL[p]) : (asL[p] * msL[p]);
    alph[t] = s;
  }
  __syncthreads();

  const unsigned int* xs = (const unsigned int*)(ws + OFF_XTS + n * 32000);
  const unsigned int* xq = (const unsigned int*)(ws + OFF_XTQ + q * 32000);
  const float als = alph[0], alq = alph[1];
  float dot = 0.f, na = 0.f, nb = 0.f;
  for (int u = t; u < 320; u += 256) {
    float s0 = 0.f, s1 = 0.f, q0 = 0.f, q1 = 0.f;
    for (int p = 0; p < 100; ++p) {
      union { unsigned int u; fp16x2 h; } a, bq;
      a.u = xs[p * 320 + u];
      bq.u = xq[p * 320 + u];
      float ap = asL[p], qp = aqL[p];
      s0 += ap * (float)a.h[0]; s1 += ap * (float)a.h[1];
      q0 += qp * (float)bq.h[0]; q1 += qp * (float)bq.h[1];
    }
    float sa0 = (s0 - als) * 0.01f, sa1 = (s1 - als) * 0.01f;
    float qa0 = (q0 - alq) * 0.01f, qa1 = (q1 - alq) * 0.01f;
    dot += sa0 * qa0 + sa1 * qa1;
    na  += sa0 * sa0 + sa1 * sa1;
    nb  += qa0 * qa0 + qa1 * qa1;
  }
  #pragma unroll
  for (int off = 32; off > 0; off >>= 1) {
    dot += __shfl_down(dot, off);
    na  += __shfl_down(na, off);
    nb  += __shfl_down(nb, off);
  }
  const int wid = t >> 6, lanei = t & 63;
  if (lanei == 0) { red[wid * 3 + 0] = dot; red[wid * 3 + 1] = na; red[wid * 3 + 2] = nb; }
  __syncthreads();
  if (t == 0) {
    dot = red[0] + red[3] + red[6] + red[9];
    na  = red[1] + red[4] + red[7] + red[10];
    nb  = red[2] + red[5] + red[8] + red[11];
    float ns = sqrtf(na); ns = ns > 1e-8f ? ns : 1e-8f;
    float nq2 = sqrtf(nb); nq2 = nq2 > 1e-8f ? nq2 : 1e-8f;
    out[it] = dot / (ns * nq2) * 5.f;   // /TEMPERATURE(0.2)
  }
}

// ---------------------------------------------------------------------------
extern "C" void kernel_launch(void* const* d_in, const int* in_sizes, int n_in,
                              void* d_out, int out_size, void* d_ws, size_t ws_size,
                              hipStream_t stream)
{
  (void)in_sizes; (void)n_in; (void)out_size; (void)ws_size;
  const float* spt    = (const float*)d_in[0];
  const float* qry    = (const float*)d_in[1];
  const float* w1x1   = (const float*)d_in[2];
  const float* bn1x1  = (const float*)d_in[3];
  const float* c1c2w  = (const float*)d_in[4];
  const float* c1bn2  = (const float*)d_in[5];
  const float* c1c1w  = (const float*)d_in[6];
  const float* c1bn1  = (const float*)d_in[7];
  const float* c1pj   = (const float*)d_in[8];
  const float* c1bnp  = (const float*)d_in[9];
  const float* c2c2w  = (const float*)d_in[10];
  const float* c2bn2  = (const float*)d_in[11];
  const float* c2c1w  = (const float*)d_in[12];
  const float* c2bn1  = (const float*)d_in[13];
  const float* c2pj   = (const float*)d_in[14];
  const float* c2bnp  = (const float*)d_in[15];
  float* ws  = (float*)d_ws;
  float* out = (float*)d_out;

  k_prep<<<1, 256, 0, stream>>>(w1x1, bn1x1,
                                c1c2w, c1bn2, c1c1w, c1bn1, c1pj, c1bnp,
                                c2c2w, c2bn2, c2c1w, c2bn1, c2pj, c2bnp,
                                ws + OFF_PRM);
  k_prepw<<<64, 256, 0, stream>>>(w1x1, ws + OFF_PRM);
  k_feat<<<80, 512, 0, stream>>>(spt, qry, ws, out);

  (void)hipFuncSetAttribute((const void*)k_cca,
                            hipFuncAttributeMaxDynamicSharedMemorySize, LDS_TOTAL);
  k_cca<<<NITEM * 2, 1024, LDS_TOTAL, stream>>>(ws);

  k_post<<<NITEM, 256, 0, stream>>>(ws, out);
}